// Round 1
// baseline (1235.425 us; speedup 1.0000x reference)
//
#include <hip/hip_runtime.h>

#define NEG_SLOPE 0.01f

// ---------------------------------------------------------------------------
// K0: zero the degree array (avoid hipMemsetAsync for graph-capture safety)
// ---------------------------------------------------------------------------
__global__ void zero_kernel(int* __restrict__ p, int n) {
    int i = blockIdx.x * blockDim.x + threadIdx.x;
    if (i < n) p[i] = 0;
}

// ---------------------------------------------------------------------------
// K1: fused projection GEMM: A[N,128] @ B[128,512]
//   col tiles 0,1 -> h (W_nodes, +bias)   [N,256]
//   col tile  2   -> P (W_edges rows 0..127)    [N,128]
//   col tile  3   -> Q (W_edges rows 135..262)  [N,128]
// 64-row tiles, 256 threads, per-thread 4x8 register block, K-chunks of 32.
// ---------------------------------------------------------------------------
__global__ __launch_bounds__(256) void gemm_proj(
    const float* __restrict__ A, const float* __restrict__ Wn,
    const float* __restrict__ bn, const float* __restrict__ We,
    float* __restrict__ h_ws, float* __restrict__ P, float* __restrict__ Q,
    int N)
{
    __shared__ float As[64][33];   // padded: conflict-free row-major reads
    __shared__ float Bs[32][128];
    int t = threadIdx.x;
    int ct = blockIdx.y;
    int row0 = blockIdx.x * 64;
    int rg = t >> 4;      // 0..15 -> rows rg*4..rg*4+3
    int cg = t & 15;      // 0..15 -> cols cg*8..cg*8+7

    float acc[4][8];
    #pragma unroll
    for (int i = 0; i < 4; i++)
        #pragma unroll
        for (int j = 0; j < 8; j++) acc[i][j] = 0.f;

    for (int k0 = 0; k0 < 128; k0 += 32) {
        // A tile 64x32 (row < N guard, zero-pad)
        #pragma unroll
        for (int i = 0; i < 8; i++) {
            int idx = t + i * 256;
            int r = idx >> 5, kk = idx & 31;
            int row = row0 + r;
            As[r][kk] = (row < N) ? A[(size_t)row * 128 + k0 + kk] : 0.f;
        }
        // B tile 32x128
        #pragma unroll
        for (int i = 0; i < 16; i++) {
            int idx = t + i * 256;
            int kr = idx >> 7, c = idx & 127;
            int k = k0 + kr;
            float v;
            if (ct < 2)       v = Wn[(size_t)k * 256 + ct * 128 + c];
            else if (ct == 2) v = We[(size_t)k * 128 + c];
            else              v = We[(size_t)(135 + k) * 128 + c];
            Bs[kr][c] = v;
        }
        __syncthreads();
        #pragma unroll
        for (int kk = 0; kk < 32; kk++) {
            float a[4], b[8];
            #pragma unroll
            for (int i = 0; i < 4; i++) a[i] = As[rg * 4 + i][kk];
            #pragma unroll
            for (int j = 0; j < 8; j++) b[j] = Bs[kk][cg * 8 + j];
            #pragma unroll
            for (int i = 0; i < 4; i++)
                #pragma unroll
                for (int j = 0; j < 8; j++) acc[i][j] += a[i] * b[j];
        }
        __syncthreads();
    }

    #pragma unroll
    for (int i = 0; i < 4; i++) {
        int row = row0 + rg * 4 + i;
        if (row >= N) continue;
        #pragma unroll
        for (int j = 0; j < 8; j++) {
            int c = cg * 8 + j;
            float v = acc[i][j];
            if (ct < 2)       h_ws[(size_t)row * 256 + ct * 128 + c] = v + bn[ct * 128 + c];
            else if (ct == 2) P[(size_t)row * 128 + c] = v;
            else              Q[(size_t)row * 128 + c] = v;
        }
    }
}

// ---------------------------------------------------------------------------
// K2: per-destination degree count
// ---------------------------------------------------------------------------
__global__ void count_kernel(const int* __restrict__ dst, int* __restrict__ deg, int E) {
    int i = blockIdx.x * blockDim.x + threadIdx.x;
    if (i < E) atomicAdd(&deg[dst[i]], 1);
}

// ---------------------------------------------------------------------------
// K3: exclusive prefix sum over deg[0..n-1] -> row_start, cursor; row_start[n]=E
// Single block, 1024 threads, chunked Hillis-Steele.
// ---------------------------------------------------------------------------
__global__ __launch_bounds__(1024) void scan_kernel(
    const int* __restrict__ deg, int* __restrict__ row_start,
    int* __restrict__ cursor, int n)
{
    __shared__ int buf[1024];
    __shared__ int carry_s;
    int t = threadIdx.x;
    if (t == 0) carry_s = 0;
    __syncthreads();
    for (int base = 0; base < n; base += 1024) {
        int i = base + t;
        int x = (i < n) ? deg[i] : 0;
        buf[t] = x;
        __syncthreads();
        for (int off = 1; off < 1024; off <<= 1) {
            int v = (t >= off) ? buf[t - off] : 0;
            __syncthreads();
            buf[t] += v;
            __syncthreads();
        }
        int carry = carry_s;
        if (i < n) {
            int ex = carry + buf[t] - x;
            row_start[i] = ex;
            cursor[i]    = ex;
        }
        __syncthreads();
        if (t == 1023) carry_s = carry + buf[t];
        __syncthreads();
    }
    if (t == 0) row_start[n] = carry_s;
}

// ---------------------------------------------------------------------------
// K4: scatter edge ids into CSR slots
// ---------------------------------------------------------------------------
__global__ void scatter_kernel(const int* __restrict__ dst, int* __restrict__ cursor,
                               int* __restrict__ eidx, int E) {
    int i = blockIdx.x * blockDim.x + threadIdx.x;
    if (i < E) {
        int pos = atomicAdd(&cursor[dst[i]], 1);
        eidx[pos] = i;
    }
}

// ---------------------------------------------------------------------------
// K5: edge kernel. 2 edges per 256-thread block; thread -> (sub=t/128, c=t%128).
//   f = leaky_relu(P[src] + Q[dst] + efeats @ W_ef)   -> f_out  [E,128]
//   a[e,h] = f[e, h*32:(h+1)*32] . w                   -> a_buf [E,4]
//   (w[j] = sum_k W_attn[k,j] -- einsum sums over both k and j)
// ---------------------------------------------------------------------------
__global__ __launch_bounds__(256) void edge_kernel(
    const float* __restrict__ P, const float* __restrict__ Q,
    const float* __restrict__ ef, const int* __restrict__ src,
    const int* __restrict__ dst, const float* __restrict__ We,
    const float* __restrict__ Wa, float* __restrict__ f_out,
    float* __restrict__ a_buf, int E)
{
    __shared__ float Wf[7][128];
    __shared__ float wv[32];
    __shared__ float efs[2][7];
    int t = threadIdx.x;
    for (int idx = t; idx < 896; idx += 256)
        Wf[idx >> 7][idx & 127] = We[(size_t)(128 + (idx >> 7)) * 128 + (idx & 127)];
    if (t < 32) wv[t] = Wa[t] + Wa[32 + t] + Wa[64 + t] + Wa[96 + t];

    size_t e0 = (size_t)blockIdx.x * 2;
    int sub = t >> 7, c = t & 127;
    size_t e = e0 + sub;
    if (t < 7 && e0 < (size_t)E)                 efs[0][t] = ef[e0 * 7 + t];
    if (t >= 128 && t < 135 && e0 + 1 < (size_t)E) efs[1][t - 128] = ef[(e0 + 1) * 7 + (t - 128)];
    __syncthreads();
    if (e >= (size_t)E) return;

    int s = src[e], d = dst[e];
    float acc = P[(size_t)s * 128 + c] + Q[(size_t)d * 128 + c];
    #pragma unroll
    for (int j = 0; j < 7; j++) acc += efs[sub][j] * Wf[j][c];
    float v = acc > 0.f ? acc : NEG_SLOPE * acc;
    f_out[e * 128 + c] = v;

    float p = v * wv[c & 31];
    #pragma unroll
    for (int m = 16; m >= 1; m >>= 1) p += __shfl_xor(p, m);
    if ((c & 31) == 0) a_buf[e * 4 + (c >> 5)] = p;
}

// ---------------------------------------------------------------------------
// K6: per-destination-node softmax + aggregation. One 256-thread block/node.
//   wave 0: online-softmax (max, sum) over the node's CSR edge list
//   all threads: acc[t] = sum_e alpha[e, t/64] * h[src[e]][t],  t = h*64+d
// ---------------------------------------------------------------------------
#define CH 256
__global__ __launch_bounds__(256) void agg_kernel(
    const int* __restrict__ row_start, const int* __restrict__ eidx,
    const int* __restrict__ src, const float* __restrict__ a_buf,
    const float* __restrict__ hfeat, float* __restrict__ out, int N)
{
    int n = blockIdx.x;
    int start = row_start[n], end = row_start[n + 1];
    int deg = end - start;
    int t = threadIdx.x;
    if (deg == 0) { out[(size_t)n * 256 + t] = 0.f; return; }

    __shared__ float amax_s[4], rden_s[4];
    __shared__ int   se_s[CH];
    __shared__ float alpha_s[CH][4];

    if (t < 64) {
        float m[4], ss[4];
        #pragma unroll
        for (int h = 0; h < 4; h++) { m[h] = -1e30f; ss[h] = 0.f; }
        for (int i = t; i < deg; i += 64) {
            int e = eidx[start + i];
            #pragma unroll
            for (int h = 0; h < 4; h++) {
                float a  = a_buf[(size_t)e * 4 + h];
                float nm = fmaxf(m[h], a);
                ss[h] = ss[h] * __expf(m[h] - nm) + __expf(a - nm);
                m[h]  = nm;
            }
        }
        #pragma unroll
        for (int off = 32; off >= 1; off >>= 1) {
            #pragma unroll
            for (int h = 0; h < 4; h++) {
                float om = __shfl_xor(m[h], off);
                float os = __shfl_xor(ss[h], off);
                float nm = fmaxf(m[h], om);
                ss[h] = ss[h] * __expf(m[h] - nm) + os * __expf(om - nm);
                m[h]  = nm;
            }
        }
        if (t == 0) {
            #pragma unroll
            for (int h = 0; h < 4; h++) { amax_s[h] = m[h]; rden_s[h] = 1.f / ss[h]; }
        }
    }
    __syncthreads();

    int h = t >> 6;
    float acc = 0.f;
    for (int cs = 0; cs < deg; cs += CH) {
        int clen = min(CH, deg - cs);
        if (t < clen) {
            int e = eidx[start + cs + t];
            se_s[t] = src[e];
            #pragma unroll
            for (int hh = 0; hh < 4; hh++)
                alpha_s[t][hh] = __expf(a_buf[(size_t)e * 4 + hh] - amax_s[hh]) * rden_s[hh];
        }
        __syncthreads();
        for (int i = 0; i < clen; i++)
            acc += alpha_s[i][h] * hfeat[(size_t)se_s[i] * 256 + t];
        __syncthreads();
    }
    out[(size_t)n * 256 + t] = acc;
}

// ---------------------------------------------------------------------------
extern "C" void kernel_launch(void* const* d_in, const int* in_sizes, int n_in,
                              void* d_out, int out_size, void* d_ws, size_t ws_size,
                              hipStream_t stream)
{
    const float* nfeats = (const float*)d_in[0];
    const float* efeats = (const float*)d_in[1];
    const int*   src    = (const int*)d_in[2];
    const int*   dst    = (const int*)d_in[3];
    const float* Wn     = (const float*)d_in[4];
    const float* bn     = (const float*)d_in[5];
    const float* We     = (const float*)d_in[6];
    const float* Wa     = (const float*)d_in[7];

    int N = in_sizes[0] / 128;
    int E = in_sizes[2];

    char* ws = (char*)d_ws;
    size_t off = 0;
    float* h_ws  = (float*)(ws + off); off += (size_t)N * 256 * 4;
    float* P     = (float*)(ws + off); off += (size_t)N * 128 * 4;
    float* Qp    = (float*)(ws + off); off += (size_t)N * 128 * 4;
    float* a_buf = (float*)(ws + off); off += (size_t)E * 4 * 4;
    int* deg       = (int*)(ws + off); off += (size_t)(N + 1) * 4;
    int* row_start = (int*)(ws + off); off += (size_t)(N + 1) * 4;
    int* cursor    = (int*)(ws + off); off += (size_t)(N + 1) * 4;
    int* eidx      = (int*)(ws + off); off += (size_t)E * 4;

    float* h_out = (float*)d_out;                       // [N, 4, 64]
    float* f_out = (float*)d_out + (size_t)N * 256;     // [E, 4, 32]

    zero_kernel<<<(N + 255) / 256, 256, 0, stream>>>(deg, N);

    dim3 g2((N + 63) / 64, 4);
    gemm_proj<<<g2, 256, 0, stream>>>(nfeats, Wn, bn, We, h_ws, P, Qp, N);

    count_kernel<<<(E + 255) / 256, 256, 0, stream>>>(dst, deg, E);
    scan_kernel<<<1, 1024, 0, stream>>>(deg, row_start, cursor, N);
    scatter_kernel<<<(E + 255) / 256, 256, 0, stream>>>(dst, cursor, eidx, E);

    edge_kernel<<<(E + 1) / 2, 256, 0, stream>>>(P, Qp, efeats, src, dst, We, Wa,
                                                 f_out, a_buf, E);

    agg_kernel<<<N, 256, 0, stream>>>(row_start, eidx, src, a_buf, h_ws, h_out, N);
}

// Round 2
// 757.710 us; speedup vs baseline: 1.6305x; 1.6305x over previous
//
#include <hip/hip_runtime.h>

#define NEG_SLOPE 0.01f

// ---------------------------------------------------------------------------
// K0: zero the degree array
// ---------------------------------------------------------------------------
__global__ void zero_kernel(int* __restrict__ p, int n) {
    int i = blockIdx.x * blockDim.x + threadIdx.x;
    if (i < n) p[i] = 0;
}

// ---------------------------------------------------------------------------
// K1: fused projection GEMM: A[N,128] @ B[128,512]
//   col tiles 0,1 -> h (W_nodes, +bias)   [N,256]
//   col tile  2   -> P (W_edges rows 0..127)    [N,128]
//   col tile  3   -> Q (W_edges rows 135..262)  [N,128]
// ---------------------------------------------------------------------------
__global__ __launch_bounds__(256) void gemm_proj(
    const float* __restrict__ A, const float* __restrict__ Wn,
    const float* __restrict__ bn, const float* __restrict__ We,
    float* __restrict__ h_ws, float* __restrict__ P, float* __restrict__ Q,
    int N)
{
    __shared__ float As[64][33];
    __shared__ float Bs[32][128];
    int t = threadIdx.x;
    int ct = blockIdx.y;
    int row0 = blockIdx.x * 64;
    int rg = t >> 4;
    int cg = t & 15;

    float acc[4][8];
    #pragma unroll
    for (int i = 0; i < 4; i++)
        #pragma unroll
        for (int j = 0; j < 8; j++) acc[i][j] = 0.f;

    for (int k0 = 0; k0 < 128; k0 += 32) {
        #pragma unroll
        for (int i = 0; i < 8; i++) {
            int idx = t + i * 256;
            int r = idx >> 5, kk = idx & 31;
            int row = row0 + r;
            As[r][kk] = (row < N) ? A[(size_t)row * 128 + k0 + kk] : 0.f;
        }
        #pragma unroll
        for (int i = 0; i < 16; i++) {
            int idx = t + i * 256;
            int kr = idx >> 7, c = idx & 127;
            int k = k0 + kr;
            float v;
            if (ct < 2)       v = Wn[(size_t)k * 256 + ct * 128 + c];
            else if (ct == 2) v = We[(size_t)k * 128 + c];
            else              v = We[(size_t)(135 + k) * 128 + c];
            Bs[kr][c] = v;
        }
        __syncthreads();
        #pragma unroll
        for (int kk = 0; kk < 32; kk++) {
            float a[4], b[8];
            #pragma unroll
            for (int i = 0; i < 4; i++) a[i] = As[rg * 4 + i][kk];
            #pragma unroll
            for (int j = 0; j < 8; j++) b[j] = Bs[kk][cg * 8 + j];
            #pragma unroll
            for (int i = 0; i < 4; i++)
                #pragma unroll
                for (int j = 0; j < 8; j++) acc[i][j] += a[i] * b[j];
        }
        __syncthreads();
    }

    #pragma unroll
    for (int i = 0; i < 4; i++) {
        int row = row0 + rg * 4 + i;
        if (row >= N) continue;
        #pragma unroll
        for (int j = 0; j < 8; j++) {
            int c = cg * 8 + j;
            float v = acc[i][j];
            if (ct < 2)       h_ws[(size_t)row * 256 + ct * 128 + c] = v + bn[ct * 128 + c];
            else if (ct == 2) P[(size_t)row * 128 + c] = v;
            else              Q[(size_t)row * 128 + c] = v;
        }
    }
}

// ---------------------------------------------------------------------------
// K2: per-destination degree count
// ---------------------------------------------------------------------------
__global__ void count_kernel(const int* __restrict__ dst, int* __restrict__ deg, int E) {
    int i = blockIdx.x * blockDim.x + threadIdx.x;
    if (i < E) atomicAdd(&deg[dst[i]], 1);
}

// ---------------------------------------------------------------------------
// K3a/b/c: multi-block exclusive scan of deg -> row_start, cursor
// ---------------------------------------------------------------------------
__global__ __launch_bounds__(256) void scan_sum(
    const int* __restrict__ deg, int* __restrict__ bsum, int n)
{
    int b = blockIdx.x, t = threadIdx.x;
    int base = b * 1024 + t * 4;
    int s = 0;
    #pragma unroll
    for (int k = 0; k < 4; k++) { int i = base + k; if (i < n) s += deg[i]; }
    #pragma unroll
    for (int off = 32; off >= 1; off >>= 1) s += __shfl_xor(s, off);
    __shared__ int ws[4];
    if ((t & 63) == 0) ws[t >> 6] = s;
    __syncthreads();
    if (t == 0) bsum[b] = ws[0] + ws[1] + ws[2] + ws[3];
}

__global__ void scan_offsets(const int* __restrict__ bsum, int* __restrict__ boff,
                             int nb, int* __restrict__ row_start, int n)
{
    int acc = 0;
    for (int b = 0; b < nb; b++) { boff[b] = acc; acc += bsum[b]; }
    row_start[n] = acc;
}

__global__ __launch_bounds__(256) void scan_write(
    const int* __restrict__ deg, const int* __restrict__ boff,
    int* __restrict__ row_start, int* __restrict__ cursor, int n)
{
    int b = blockIdx.x, t = threadIdx.x, lane = t & 63, w = t >> 6;
    int base = b * 1024 + t * 4;
    int x0, x1, x2, x3;
    x0 = (base + 0 < n) ? deg[base + 0] : 0;
    x1 = (base + 1 < n) ? deg[base + 1] : 0;
    x2 = (base + 2 < n) ? deg[base + 2] : 0;
    x3 = (base + 3 < n) ? deg[base + 3] : 0;
    int tsum = x0 + x1 + x2 + x3;
    int inc = tsum;
    #pragma unroll
    for (int off = 1; off < 64; off <<= 1) {
        int v = __shfl_up(inc, off);
        if (lane >= off) inc += v;
    }
    int texcl = inc - tsum;
    __shared__ int wsum[4];
    if (lane == 63) wsum[w] = inc;
    __syncthreads();
    int wexcl = 0;
    #pragma unroll
    for (int ww = 0; ww < 4; ww++) if (ww < w) wexcl += wsum[ww];
    int basev = boff[b] + wexcl + texcl;
    int p0 = basev;
    int p1 = p0 + x0;
    int p2 = p1 + x1;
    int p3 = p2 + x2;
    if (base + 0 < n) { row_start[base + 0] = p0; cursor[base + 0] = p0; }
    if (base + 1 < n) { row_start[base + 1] = p1; cursor[base + 1] = p1; }
    if (base + 2 < n) { row_start[base + 2] = p2; cursor[base + 2] = p2; }
    if (base + 3 < n) { row_start[base + 3] = p3; cursor[base + 3] = p3; }
}

// ---------------------------------------------------------------------------
// K4: scatter edge ids into CSR slots
// ---------------------------------------------------------------------------
__global__ void scatter_kernel(const int* __restrict__ dst, int* __restrict__ cursor,
                               int* __restrict__ eidx, int E) {
    int i = blockIdx.x * blockDim.x + threadIdx.x;
    if (i < E) {
        int pos = atomicAdd(&cursor[dst[i]], 1);
        eidx[pos] = i;
    }
}

// ---------------------------------------------------------------------------
// K5: edge kernel. Persistent waves; 1 edge per wave per iter; 2 cols/lane.
// Weights in registers, zero LDS, no barriers. Nontemporal f_out stores.
// ---------------------------------------------------------------------------
__global__ __launch_bounds__(256) void edge_kernel(
    const float* __restrict__ P, const float* __restrict__ Q,
    const float* __restrict__ ef, const int* __restrict__ src,
    const int* __restrict__ dst, const float* __restrict__ We,
    const float* __restrict__ Wa, float* __restrict__ f_out,
    float* __restrict__ a_buf, int E)
{
    int t = threadIdx.x;
    int lane = t & 63;
    int gw = (int)((blockIdx.x * blockDim.x + t) >> 6);
    int nw = (int)((gridDim.x * blockDim.x) >> 6);
    int c0 = lane * 2;

    float wf0[7], wf1[7];
    #pragma unroll
    for (int j = 0; j < 7; j++) {
        wf0[j] = We[(size_t)(128 + j) * 128 + c0];
        wf1[j] = We[(size_t)(128 + j) * 128 + c0 + 1];
    }
    int j0 = c0 & 31, j1 = (c0 + 1) & 31;
    float wv0 = Wa[j0] + Wa[32 + j0] + Wa[64 + j0] + Wa[96 + j0];
    float wv1 = Wa[j1] + Wa[32 + j1] + Wa[64 + j1] + Wa[96 + j1];

    const float2* P2 = (const float2*)P;
    const float2* Q2 = (const float2*)Q;

    for (size_t e = (size_t)gw; e < (size_t)E; e += (size_t)nw) {
        int s = src[e], d = dst[e];
        float2 pv = P2[(size_t)s * 64 + lane];
        float2 qv = Q2[(size_t)d * 64 + lane];
        float acc0 = pv.x + qv.x;
        float acc1 = pv.y + qv.y;
        #pragma unroll
        for (int j = 0; j < 7; j++) {
            float efv = ef[e * 7 + j];
            acc0 = fmaf(efv, wf0[j], acc0);
            acc1 = fmaf(efv, wf1[j], acc1);
        }
        float v0 = acc0 > 0.f ? acc0 : NEG_SLOPE * acc0;
        float v1 = acc1 > 0.f ? acc1 : NEG_SLOPE * acc1;

        float2 fv = make_float2(v0, v1);
        unsigned long long u;
        __builtin_memcpy(&u, &fv, 8);
        __builtin_nontemporal_store(u, (unsigned long long*)(f_out + e * 128 + c0));

        float p = fmaf(v0, wv0, v1 * wv1);
        p += __shfl_xor(p, 8);
        p += __shfl_xor(p, 4);
        p += __shfl_xor(p, 2);
        p += __shfl_xor(p, 1);
        if ((lane & 15) == 0) a_buf[e * 4 + (lane >> 4)] = p;
    }
}

// ---------------------------------------------------------------------------
// K6: softmax + aggregation, one wave per node, float4 per lane, no barriers.
// ---------------------------------------------------------------------------
__global__ __launch_bounds__(256) void agg_kernel(
    const int* __restrict__ row_start, const int* __restrict__ eidx,
    const int* __restrict__ src, const float* __restrict__ a_buf,
    const float* __restrict__ hfeat, float* __restrict__ out, int N)
{
    int t = threadIdx.x;
    int lane = t & 63;
    int n = (int)((blockIdx.x * blockDim.x + t) >> 6);
    if (n >= N) return;

    int start = row_start[n], end = row_start[n + 1];
    int deg = end - start;
    int h = lane >> 4;
    const float4* H4 = (const float4*)hfeat;
    float4* O4 = (float4*)out;

    if (deg == 0) {
        O4[(size_t)n * 64 + lane] = make_float4(0.f, 0.f, 0.f, 0.f);
        return;
    }

    // phase 1: per-head online softmax stats across the wave
    float m0 = -1e30f, m1 = -1e30f, m2 = -1e30f, m3 = -1e30f;
    float s0 = 0.f, s1 = 0.f, s2 = 0.f, s3 = 0.f;
    const float4* A4 = (const float4*)a_buf;
    for (int i = lane; i < deg; i += 64) {
        int e = eidx[start + i];
        float4 a = A4[e];
        float nm;
        nm = fmaxf(m0, a.x); s0 = s0 * __expf(m0 - nm) + __expf(a.x - nm); m0 = nm;
        nm = fmaxf(m1, a.y); s1 = s1 * __expf(m1 - nm) + __expf(a.y - nm); m1 = nm;
        nm = fmaxf(m2, a.z); s2 = s2 * __expf(m2 - nm) + __expf(a.z - nm); m2 = nm;
        nm = fmaxf(m3, a.w); s3 = s3 * __expf(m3 - nm) + __expf(a.w - nm); m3 = nm;
    }
    #pragma unroll
    for (int off = 32; off >= 1; off >>= 1) {
        float om, os, nm;
        om = __shfl_xor(m0, off); os = __shfl_xor(s0, off);
        nm = fmaxf(m0, om); s0 = s0 * __expf(m0 - nm) + os * __expf(om - nm); m0 = nm;
        om = __shfl_xor(m1, off); os = __shfl_xor(s1, off);
        nm = fmaxf(m1, om); s1 = s1 * __expf(m1 - nm) + os * __expf(om - nm); m1 = nm;
        om = __shfl_xor(m2, off); os = __shfl_xor(s2, off);
        nm = fmaxf(m2, om); s2 = s2 * __expf(m2 - nm) + os * __expf(om - nm); m2 = nm;
        om = __shfl_xor(m3, off); os = __shfl_xor(s3, off);
        nm = fmaxf(m3, om); s3 = s3 * __expf(m3 - nm) + os * __expf(om - nm); m3 = nm;
    }
    float mh   = (h < 2) ? ((h == 0) ? m0 : m1) : ((h == 2) ? m2 : m3);
    float sh   = (h < 2) ? ((h == 0) ? s0 : s1) : ((h == 2) ? s2 : s3);
    float rden = 1.f / sh;

    // phase 2: weighted aggregation
    float4 acc = make_float4(0.f, 0.f, 0.f, 0.f);
    for (int i = 0; i < deg; i++) {
        int e = eidx[start + i];
        int s = src[e];
        float av = a_buf[(size_t)e * 4 + h];
        float alpha = __expf(av - mh) * rden;
        float4 hv = H4[(size_t)s * 64 + lane];
        acc.x = fmaf(alpha, hv.x, acc.x);
        acc.y = fmaf(alpha, hv.y, acc.y);
        acc.z = fmaf(alpha, hv.z, acc.z);
        acc.w = fmaf(alpha, hv.w, acc.w);
    }
    O4[(size_t)n * 64 + lane] = acc;
}

// ---------------------------------------------------------------------------
extern "C" void kernel_launch(void* const* d_in, const int* in_sizes, int n_in,
                              void* d_out, int out_size, void* d_ws, size_t ws_size,
                              hipStream_t stream)
{
    const float* nfeats = (const float*)d_in[0];
    const float* efeats = (const float*)d_in[1];
    const int*   src    = (const int*)d_in[2];
    const int*   dst    = (const int*)d_in[3];
    const float* Wn     = (const float*)d_in[4];
    const float* bn     = (const float*)d_in[5];
    const float* We     = (const float*)d_in[6];
    const float* Wa     = (const float*)d_in[7];

    int N = in_sizes[0] / 128;
    int E = in_sizes[2];

    char* ws = (char*)d_ws;
    size_t off = 0;
    float* h_ws  = (float*)(ws + off); off += (size_t)N * 256 * 4;
    float* P     = (float*)(ws + off); off += (size_t)N * 128 * 4;
    float* Qp    = (float*)(ws + off); off += (size_t)N * 128 * 4;
    float* a_buf = (float*)(ws + off); off += (size_t)E * 4 * 4;
    int* eidx      = (int*)(ws + off); off += (size_t)E * 4;
    int* deg       = (int*)(ws + off); off += (size_t)(N + 1) * 4;
    int* row_start = (int*)(ws + off); off += (size_t)(N + 1) * 4;
    int* cursor    = (int*)(ws + off); off += (size_t)(N + 1) * 4;
    int* bsum      = (int*)(ws + off); off += 1024;
    int* boff      = (int*)(ws + off); off += 1024;

    float* h_out = (float*)d_out;                       // [N, 4, 64]
    float* f_out = (float*)d_out + (size_t)N * 256;     // [E, 4, 32]

    zero_kernel<<<(N + 255) / 256, 256, 0, stream>>>(deg, N);

    dim3 g2((N + 63) / 64, 4);
    gemm_proj<<<g2, 256, 0, stream>>>(nfeats, Wn, bn, We, h_ws, P, Qp, N);

    count_kernel<<<(E + 255) / 256, 256, 0, stream>>>(dst, deg, E);

    int nb = (N + 1023) / 1024;
    scan_sum<<<nb, 256, 0, stream>>>(deg, bsum, N);
    scan_offsets<<<1, 1, 0, stream>>>(bsum, boff, nb, row_start, N);
    scan_write<<<nb, 256, 0, stream>>>(deg, boff, row_start, cursor, N);

    scatter_kernel<<<(E + 255) / 256, 256, 0, stream>>>(dst, cursor, eidx, E);

    edge_kernel<<<4096, 256, 0, stream>>>(P, Qp, efeats, src, dst, We, Wa,
                                          f_out, a_buf, E);

    agg_kernel<<<(N + 3) / 4, 256, 0, stream>>>(row_start, eidx, src, a_buf,
                                                h_ws, h_out, N);
}

// Round 3
// 495.925 us; speedup vs baseline: 2.4912x; 1.5279x over previous
//
#include <hip/hip_runtime.h>

#define NEG_SLOPE 0.01f

typedef __attribute__((ext_vector_type(8))) __bf16 bf16x8;
typedef __attribute__((ext_vector_type(4))) float  f32x4;

__device__ __forceinline__ unsigned short f2bf(float x) {
    unsigned u; __builtin_memcpy(&u, &x, 4);
    unsigned r = u + 0x7FFFu + ((u >> 16) & 1u);   // RNE
    return (unsigned short)(r >> 16);
}

// ---------------------------------------------------------------------------
// K0: zero the degree array
// ---------------------------------------------------------------------------
__global__ void zero_kernel(int* __restrict__ p, int n) {
    int i = blockIdx.x * blockDim.x + threadIdx.x;
    if (i < n) p[i] = 0;
}

// ---------------------------------------------------------------------------
// K1a: pack all 512 projection columns as B^T bf16 [n=512][k=128].
//   n 0..255   -> W_nodes col n          (h)
//   n 256..383 -> W_edges rows 0..127    (P)
//   n 384..511 -> W_edges rows 135..262  (Q)
// ---------------------------------------------------------------------------
__global__ __launch_bounds__(256) void bt_prep(
    const float* __restrict__ Wn, const float* __restrict__ We,
    short* __restrict__ Btg)
{
    int idx = blockIdx.x * 256 + threadIdx.x;   // 0..65535
    int n = idx >> 7, k = idx & 127;
    float v;
    if (n < 256)      v = Wn[(size_t)k * 256 + n];
    else if (n < 384) v = We[(size_t)k * 128 + (n - 256)];
    else              v = We[(size_t)(135 + k) * 128 + (n - 384)];
    Btg[(size_t)n * 128 + k] = (short)f2bf(v);
}

// ---------------------------------------------------------------------------
// K1b: MFMA projection GEMM: A[N,128](fp32->bf16) @ B[128,512] -> h|P|Q
// One block: 128 rows x (4 col-tiles of 128). 4 waves, acc[2][8] 16x16 frags.
// LDS [128][136] bf16 (pad+8 -> conflict-free b128 reads).
// ---------------------------------------------------------------------------
__global__ __launch_bounds__(256) void gemm_mfma(
    const float* __restrict__ A, const float* __restrict__ bn,
    const short* __restrict__ Btg, float* __restrict__ h_ws,
    float* __restrict__ P, float* __restrict__ Q, int N)
{
    __shared__ __align__(16) short Al[128 * 136];
    __shared__ __align__(16) short Bl[128 * 136];
    int t = threadIdx.x;
    int row0 = blockIdx.x * 128;

    // stage A tile: 128x128 fp32 -> bf16
    #pragma unroll
    for (int i = 0; i < 16; i++) {
        int idx = t + i * 256;          // 4096 float4 units
        int fr = idx >> 5, fc4 = idx & 31;
        int row = row0 + fr;
        float4 v = make_float4(0.f, 0.f, 0.f, 0.f);
        if (row < N) v = *(const float4*)(A + (size_t)row * 128 + fc4 * 4);
        unsigned long long pk =  (unsigned long long)f2bf(v.x)
                              | ((unsigned long long)f2bf(v.y) << 16)
                              | ((unsigned long long)f2bf(v.z) << 32)
                              | ((unsigned long long)f2bf(v.w) << 48);
        *(unsigned long long*)&Al[fr * 136 + fc4 * 4] = pk;
    }
    __syncthreads();

    int w = t >> 6, l = t & 63;
    int lr = l & 15, lg = l >> 4;

    for (int ct = 0; ct < 4; ct++) {
        if (ct > 0) __syncthreads();    // all waves done reading Bl
        // stage B^T tile (already bf16): rows n=col, 128 x 128
        #pragma unroll
        for (int i = 0; i < 8; i++) {
            int idx = t + i * 256;      // 2048 16B units
            int r = idx >> 4, c8 = idx & 15;
            uint4 v = *(const uint4*)(Btg + (size_t)(ct * 128 + r) * 128 + c8 * 8);
            *(uint4*)&Bl[r * 136 + c8 * 8] = v;
        }
        __syncthreads();

        f32x4 acc[2][8];
        #pragma unroll
        for (int fr = 0; fr < 2; fr++)
            #pragma unroll
            for (int fc = 0; fc < 8; fc++) {
                acc[fr][fc][0] = 0.f; acc[fr][fc][1] = 0.f;
                acc[fr][fc][2] = 0.f; acc[fr][fc][3] = 0.f;
            }

        #pragma unroll
        for (int ks = 0; ks < 4; ks++) {
            int k0 = ks * 32 + lg * 8;
            bf16x8 a0 = *(const bf16x8*)&Al[(w * 32 + lr) * 136 + k0];
            bf16x8 a1 = *(const bf16x8*)&Al[(w * 32 + 16 + lr) * 136 + k0];
            #pragma unroll
            for (int fc = 0; fc < 8; fc++) {
                bf16x8 bb = *(const bf16x8*)&Bl[(fc * 16 + lr) * 136 + k0];
                acc[0][fc] = __builtin_amdgcn_mfma_f32_16x16x32_bf16(a0, bb, acc[0][fc], 0, 0, 0);
                acc[1][fc] = __builtin_amdgcn_mfma_f32_16x16x32_bf16(a1, bb, acc[1][fc], 0, 0, 0);
            }
        }

        // epilogue: C[row][col], row=(l>>4)*4+reg (+16*fr), col=l&15 (+16*fc)
        #pragma unroll
        for (int fc = 0; fc < 8; fc++) {
            int col = fc * 16 + lr;
            float bias = (ct < 2) ? bn[ct * 128 + col] : 0.f;
            #pragma unroll
            for (int fr = 0; fr < 2; fr++) {
                #pragma unroll
                for (int b = 0; b < 4; b++) {
                    int row = row0 + w * 32 + fr * 16 + lg * 4 + b;
                    if (row >= N) continue;
                    float v = acc[fr][fc][b];
                    if (ct < 2)       h_ws[(size_t)row * 256 + ct * 128 + col] = v + bias;
                    else if (ct == 2) P[(size_t)row * 128 + col] = v;
                    else              Q[(size_t)row * 128 + col] = v;
                }
            }
        }
    }
}

// ---------------------------------------------------------------------------
// K2: per-destination degree count
// ---------------------------------------------------------------------------
__global__ void count_kernel(const int* __restrict__ dst, int* __restrict__ deg, int E) {
    int i = blockIdx.x * blockDim.x + threadIdx.x;
    if (i < E) atomicAdd(&deg[dst[i]], 1);
}

// ---------------------------------------------------------------------------
// K3a/b/c: multi-block exclusive scan of deg -> row_start, cursor
// ---------------------------------------------------------------------------
__global__ __launch_bounds__(256) void scan_sum(
    const int* __restrict__ deg, int* __restrict__ bsum, int n)
{
    int b = blockIdx.x, t = threadIdx.x;
    int base = b * 1024 + t * 4;
    int s = 0;
    #pragma unroll
    for (int k = 0; k < 4; k++) { int i = base + k; if (i < n) s += deg[i]; }
    #pragma unroll
    for (int off = 32; off >= 1; off >>= 1) s += __shfl_xor(s, off);
    __shared__ int ws[4];
    if ((t & 63) == 0) ws[t >> 6] = s;
    __syncthreads();
    if (t == 0) bsum[b] = ws[0] + ws[1] + ws[2] + ws[3];
}

__global__ void scan_offsets(const int* __restrict__ bsum, int* __restrict__ boff,
                             int nb, int* __restrict__ row_start, int n)
{
    int acc = 0;
    for (int b = 0; b < nb; b++) { boff[b] = acc; acc += bsum[b]; }
    row_start[n] = acc;
}

__global__ __launch_bounds__(256) void scan_write(
    const int* __restrict__ deg, const int* __restrict__ boff,
    int* __restrict__ row_start, int* __restrict__ cursor, int n)
{
    int b = blockIdx.x, t = threadIdx.x, lane = t & 63, w = t >> 6;
    int base = b * 1024 + t * 4;
    int x0, x1, x2, x3;
    x0 = (base + 0 < n) ? deg[base + 0] : 0;
    x1 = (base + 1 < n) ? deg[base + 1] : 0;
    x2 = (base + 2 < n) ? deg[base + 2] : 0;
    x3 = (base + 3 < n) ? deg[base + 3] : 0;
    int tsum = x0 + x1 + x2 + x3;
    int inc = tsum;
    #pragma unroll
    for (int off = 1; off < 64; off <<= 1) {
        int v = __shfl_up(inc, off);
        if (lane >= off) inc += v;
    }
    int texcl = inc - tsum;
    __shared__ int wsum[4];
    if (lane == 63) wsum[w] = inc;
    __syncthreads();
    int wexcl = 0;
    #pragma unroll
    for (int ww = 0; ww < 4; ww++) if (ww < w) wexcl += wsum[ww];
    int basev = boff[b] + wexcl + texcl;
    int p0 = basev;
    int p1 = p0 + x0;
    int p2 = p1 + x1;
    int p3 = p2 + x2;
    if (base + 0 < n) { row_start[base + 0] = p0; cursor[base + 0] = p0; }
    if (base + 1 < n) { row_start[base + 1] = p1; cursor[base + 1] = p1; }
    if (base + 2 < n) { row_start[base + 2] = p2; cursor[base + 2] = p2; }
    if (base + 3 < n) { row_start[base + 3] = p3; cursor[base + 3] = p3; }
}

// ---------------------------------------------------------------------------
// K4: scatter edge ids into CSR slots
// ---------------------------------------------------------------------------
__global__ void scatter_kernel(const int* __restrict__ dst, int* __restrict__ cursor,
                               int* __restrict__ eidx, int E) {
    int i = blockIdx.x * blockDim.x + threadIdx.x;
    if (i < E) {
        int pos = atomicAdd(&cursor[dst[i]], 1);
        eidx[pos] = i;
    }
}

// ---------------------------------------------------------------------------
// K5: edge kernel. Persistent waves; 1 edge per wave per iter; 2 cols/lane.
// ---------------------------------------------------------------------------
__global__ __launch_bounds__(256) void edge_kernel(
    const float* __restrict__ P, const float* __restrict__ Q,
    const float* __restrict__ ef, const int* __restrict__ src,
    const int* __restrict__ dst, const float* __restrict__ We,
    const float* __restrict__ Wa, float* __restrict__ f_out,
    float* __restrict__ a_buf, int E)
{
    int t = threadIdx.x;
    int lane = t & 63;
    int gw = (int)((blockIdx.x * blockDim.x + t) >> 6);
    int nw = (int)((gridDim.x * blockDim.x) >> 6);
    int c0 = lane * 2;

    float wf0[7], wf1[7];
    #pragma unroll
    for (int j = 0; j < 7; j++) {
        wf0[j] = We[(size_t)(128 + j) * 128 + c0];
        wf1[j] = We[(size_t)(128 + j) * 128 + c0 + 1];
    }
    int j0 = c0 & 31, j1 = (c0 + 1) & 31;
    float wv0 = Wa[j0] + Wa[32 + j0] + Wa[64 + j0] + Wa[96 + j0];
    float wv1 = Wa[j1] + Wa[32 + j1] + Wa[64 + j1] + Wa[96 + j1];

    const float2* P2 = (const float2*)P;
    const float2* Q2 = (const float2*)Q;

    for (size_t e = (size_t)gw; e < (size_t)E; e += (size_t)nw) {
        int s = src[e], d = dst[e];
        float2 pv = P2[(size_t)s * 64 + lane];
        float2 qv = Q2[(size_t)d * 64 + lane];
        float acc0 = pv.x + qv.x;
        float acc1 = pv.y + qv.y;
        #pragma unroll
        for (int j = 0; j < 7; j++) {
            float efv = ef[e * 7 + j];
            acc0 = fmaf(efv, wf0[j], acc0);
            acc1 = fmaf(efv, wf1[j], acc1);
        }
        float v0 = acc0 > 0.f ? acc0 : NEG_SLOPE * acc0;
        float v1 = acc1 > 0.f ? acc1 : NEG_SLOPE * acc1;

        float2 fv = make_float2(v0, v1);
        unsigned long long u;
        __builtin_memcpy(&u, &fv, 8);
        __builtin_nontemporal_store(u, (unsigned long long*)(f_out + e * 128 + c0));

        float p = fmaf(v0, wv0, v1 * wv1);
        p += __shfl_xor(p, 8);
        p += __shfl_xor(p, 4);
        p += __shfl_xor(p, 2);
        p += __shfl_xor(p, 1);
        if ((lane & 15) == 0) a_buf[e * 4 + (lane >> 4)] = p;
    }
}

// ---------------------------------------------------------------------------
// K6: softmax + aggregation, one wave per node, float4 per lane.
// ---------------------------------------------------------------------------
__global__ __launch_bounds__(256) void agg_kernel(
    const int* __restrict__ row_start, const int* __restrict__ eidx,
    const int* __restrict__ src, const float* __restrict__ a_buf,
    const float* __restrict__ hfeat, float* __restrict__ out, int N)
{
    int t = threadIdx.x;
    int lane = t & 63;
    int n = (int)((blockIdx.x * blockDim.x + t) >> 6);
    if (n >= N) return;

    int start = row_start[n], end = row_start[n + 1];
    int deg = end - start;
    int h = lane >> 4;
    const float4* H4 = (const float4*)hfeat;
    float4* O4 = (float4*)out;

    if (deg == 0) {
        O4[(size_t)n * 64 + lane] = make_float4(0.f, 0.f, 0.f, 0.f);
        return;
    }

    float m0 = -1e30f, m1 = -1e30f, m2 = -1e30f, m3 = -1e30f;
    float s0 = 0.f, s1 = 0.f, s2 = 0.f, s3 = 0.f;
    const float4* A4 = (const float4*)a_buf;
    for (int i = lane; i < deg; i += 64) {
        int e = eidx[start + i];
        float4 a = A4[e];
        float nm;
        nm = fmaxf(m0, a.x); s0 = s0 * __expf(m0 - nm) + __expf(a.x - nm); m0 = nm;
        nm = fmaxf(m1, a.y); s1 = s1 * __expf(m1 - nm) + __expf(a.y - nm); m1 = nm;
        nm = fmaxf(m2, a.z); s2 = s2 * __expf(m2 - nm) + __expf(a.z - nm); m2 = nm;
        nm = fmaxf(m3, a.w); s3 = s3 * __expf(m3 - nm) + __expf(a.w - nm); m3 = nm;
    }
    #pragma unroll
    for (int off = 32; off >= 1; off >>= 1) {
        float om, os, nm;
        om = __shfl_xor(m0, off); os = __shfl_xor(s0, off);
        nm = fmaxf(m0, om); s0 = s0 * __expf(m0 - nm) + os * __expf(om - nm); m0 = nm;
        om = __shfl_xor(m1, off); os = __shfl_xor(s1, off);
        nm = fmaxf(m1, om); s1 = s1 * __expf(m1 - nm) + os * __expf(om - nm); m1 = nm;
        om = __shfl_xor(m2, off); os = __shfl_xor(s2, off);
        nm = fmaxf(m2, om); s2 = s2 * __expf(m2 - nm) + os * __expf(om - nm); m2 = nm;
        om = __shfl_xor(m3, off); os = __shfl_xor(s3, off);
        nm = fmaxf(m3, om); s3 = s3 * __expf(m3 - nm) + os * __expf(om - nm); m3 = nm;
    }
    float mh   = (h < 2) ? ((h == 0) ? m0 : m1) : ((h == 2) ? m2 : m3);
    float sh   = (h < 2) ? ((h == 0) ? s0 : s1) : ((h == 2) ? s2 : s3);
    float rden = 1.f / sh;

    float4 acc = make_float4(0.f, 0.f, 0.f, 0.f);
    for (int i = 0; i < deg; i++) {
        int e = eidx[start + i];
        int s = src[e];
        float av = a_buf[(size_t)e * 4 + h];
        float alpha = __expf(av - mh) * rden;
        float4 hv = H4[(size_t)s * 64 + lane];
        acc.x = fmaf(alpha, hv.x, acc.x);
        acc.y = fmaf(alpha, hv.y, acc.y);
        acc.z = fmaf(alpha, hv.z, acc.z);
        acc.w = fmaf(alpha, hv.w, acc.w);
    }
    O4[(size_t)n * 64 + lane] = acc;
}

// ---------------------------------------------------------------------------
extern "C" void kernel_launch(void* const* d_in, const int* in_sizes, int n_in,
                              void* d_out, int out_size, void* d_ws, size_t ws_size,
                              hipStream_t stream)
{
    const float* nfeats = (const float*)d_in[0];
    const float* efeats = (const float*)d_in[1];
    const int*   src    = (const int*)d_in[2];
    const int*   dst    = (const int*)d_in[3];
    const float* Wn     = (const float*)d_in[4];
    const float* bn     = (const float*)d_in[5];
    const float* We     = (const float*)d_in[6];
    const float* Wa     = (const float*)d_in[7];

    int N = in_sizes[0] / 128;
    int E = in_sizes[2];

    char* ws = (char*)d_ws;
    size_t off = 0;
    float* h_ws  = (float*)(ws + off); off += (size_t)N * 256 * 4;
    float* P     = (float*)(ws + off); off += (size_t)N * 128 * 4;
    float* Qp    = (float*)(ws + off); off += (size_t)N * 128 * 4;
    float* a_buf = (float*)(ws + off); off += (size_t)E * 4 * 4;
    short* Btg   = (short*)(ws + off); off += (size_t)512 * 128 * 2;
    int* eidx      = (int*)(ws + off); off += (size_t)E * 4;
    int* deg       = (int*)(ws + off); off += (size_t)(N + 1) * 4;
    int* row_start = (int*)(ws + off); off += (size_t)(N + 1) * 4;
    int* cursor    = (int*)(ws + off); off += (size_t)(N + 1) * 4;
    int* bsum      = (int*)(ws + off); off += 1024;
    int* boff      = (int*)(ws + off); off += 1024;

    float* h_out = (float*)d_out;                       // [N, 4, 64]
    float* f_out = (float*)d_out + (size_t)N * 256;     // [E, 4, 32]

    zero_kernel<<<(N + 255) / 256, 256, 0, stream>>>(deg, N);

    bt_prep<<<256, 256, 0, stream>>>(Wn, We, Btg);
    gemm_mfma<<<(N + 127) / 128, 256, 0, stream>>>(nfeats, bn, Btg, h_ws, P, Qp, N);

    count_kernel<<<(E + 255) / 256, 256, 0, stream>>>(dst, deg, E);

    int nb = (N + 1023) / 1024;
    scan_sum<<<nb, 256, 0, stream>>>(deg, bsum, N);
    scan_offsets<<<1, 1, 0, stream>>>(bsum, boff, nb, row_start, N);
    scan_write<<<nb, 256, 0, stream>>>(deg, boff, row_start, cursor, N);

    scatter_kernel<<<(E + 255) / 256, 256, 0, stream>>>(dst, cursor, eidx, E);

    edge_kernel<<<4096, 256, 0, stream>>>(P, Qp, efeats, src, dst, We, Wa,
                                          f_out, a_buf, E);

    agg_kernel<<<(N + 3) / 4, 256, 0, stream>>>(row_start, eidx, src, a_buf,
                                                h_ws, h_out, N);
}

// Round 4
// 412.652 us; speedup vs baseline: 2.9939x; 1.2018x over previous
//
#include <hip/hip_runtime.h>

#define NEG_SLOPE 0.01f

typedef __attribute__((ext_vector_type(8))) __bf16 bf16x8;
typedef __attribute__((ext_vector_type(4))) float  f32x4;

__device__ __forceinline__ unsigned short f2bf(float x) {
    unsigned u; __builtin_memcpy(&u, &x, 4);
    unsigned r = u + 0x7FFFu + ((u >> 16) & 1u);   // RNE
    return (unsigned short)(r >> 16);
}

// ---------------------------------------------------------------------------
// K0: zero the degree array
// ---------------------------------------------------------------------------
__global__ void zero_kernel(int* __restrict__ p, int n) {
    int i = blockIdx.x * blockDim.x + threadIdx.x;
    if (i < n) p[i] = 0;
}

// ---------------------------------------------------------------------------
// K1a: pack all 512 projection columns as B^T bf16 [n=512][k=128].
// ---------------------------------------------------------------------------
__global__ __launch_bounds__(256) void bt_prep(
    const float* __restrict__ Wn, const float* __restrict__ We,
    short* __restrict__ Btg)
{
    int idx = blockIdx.x * 256 + threadIdx.x;   // 0..65535
    int n = idx >> 7, k = idx & 127;
    float v;
    if (n < 256)      v = Wn[(size_t)k * 256 + n];
    else if (n < 384) v = We[(size_t)k * 128 + (n - 256)];
    else              v = We[(size_t)(135 + k) * 128 + (n - 384)];
    Btg[(size_t)n * 128 + k] = (short)f2bf(v);
}

// ---------------------------------------------------------------------------
// K1b: MFMA projection GEMM: A[N,128](fp32->bf16) @ B[128,512] -> h|P|Q
// ---------------------------------------------------------------------------
__global__ __launch_bounds__(256) void gemm_mfma(
    const float* __restrict__ A, const float* __restrict__ bn,
    const short* __restrict__ Btg, float* __restrict__ h_ws,
    float* __restrict__ P, float* __restrict__ Q, int N)
{
    __shared__ __align__(16) short Al[128 * 136];
    __shared__ __align__(16) short Bl[128 * 136];
    int t = threadIdx.x;
    int row0 = blockIdx.x * 128;

    #pragma unroll
    for (int i = 0; i < 16; i++) {
        int idx = t + i * 256;
        int fr = idx >> 5, fc4 = idx & 31;
        int row = row0 + fr;
        float4 v = make_float4(0.f, 0.f, 0.f, 0.f);
        if (row < N) v = *(const float4*)(A + (size_t)row * 128 + fc4 * 4);
        unsigned long long pk =  (unsigned long long)f2bf(v.x)
                              | ((unsigned long long)f2bf(v.y) << 16)
                              | ((unsigned long long)f2bf(v.z) << 32)
                              | ((unsigned long long)f2bf(v.w) << 48);
        *(unsigned long long*)&Al[fr * 136 + fc4 * 4] = pk;
    }
    __syncthreads();

    int w = t >> 6, l = t & 63;
    int lr = l & 15, lg = l >> 4;

    for (int ct = 0; ct < 4; ct++) {
        if (ct > 0) __syncthreads();
        #pragma unroll
        for (int i = 0; i < 8; i++) {
            int idx = t + i * 256;
            int r = idx >> 4, c8 = idx & 15;
            uint4 v = *(const uint4*)(Btg + (size_t)(ct * 128 + r) * 128 + c8 * 8);
            *(uint4*)&Bl[r * 136 + c8 * 8] = v;
        }
        __syncthreads();

        f32x4 acc[2][8];
        #pragma unroll
        for (int fr = 0; fr < 2; fr++)
            #pragma unroll
            for (int fc = 0; fc < 8; fc++) {
                acc[fr][fc][0] = 0.f; acc[fr][fc][1] = 0.f;
                acc[fr][fc][2] = 0.f; acc[fr][fc][3] = 0.f;
            }

        #pragma unroll
        for (int ks = 0; ks < 4; ks++) {
            int k0 = ks * 32 + lg * 8;
            bf16x8 a0 = *(const bf16x8*)&Al[(w * 32 + lr) * 136 + k0];
            bf16x8 a1 = *(const bf16x8*)&Al[(w * 32 + 16 + lr) * 136 + k0];
            #pragma unroll
            for (int fc = 0; fc < 8; fc++) {
                bf16x8 bb = *(const bf16x8*)&Bl[(fc * 16 + lr) * 136 + k0];
                acc[0][fc] = __builtin_amdgcn_mfma_f32_16x16x32_bf16(a0, bb, acc[0][fc], 0, 0, 0);
                acc[1][fc] = __builtin_amdgcn_mfma_f32_16x16x32_bf16(a1, bb, acc[1][fc], 0, 0, 0);
            }
        }

        #pragma unroll
        for (int fc = 0; fc < 8; fc++) {
            int col = fc * 16 + lr;
            float bias = (ct < 2) ? bn[ct * 128 + col] : 0.f;
            #pragma unroll
            for (int fr = 0; fr < 2; fr++) {
                #pragma unroll
                for (int b = 0; b < 4; b++) {
                    int row = row0 + w * 32 + fr * 16 + lg * 4 + b;
                    if (row >= N) continue;
                    float v = acc[fr][fc][b];
                    if (ct < 2)       h_ws[(size_t)row * 256 + ct * 128 + col] = v + bias;
                    else if (ct == 2) P[(size_t)row * 128 + col] = v;
                    else              Q[(size_t)row * 128 + col] = v;
                }
            }
        }
    }
}

// ---------------------------------------------------------------------------
// K2: per-destination degree count
// ---------------------------------------------------------------------------
__global__ void count_kernel(const int* __restrict__ dst, int* __restrict__ deg, int E) {
    int i = blockIdx.x * blockDim.x + threadIdx.x;
    if (i < E) atomicAdd(&deg[dst[i]], 1);
}

// ---------------------------------------------------------------------------
// K3a/b/c: multi-block exclusive scan of deg -> row_start, cursor
// ---------------------------------------------------------------------------
__global__ __launch_bounds__(256) void scan_sum(
    const int* __restrict__ deg, int* __restrict__ bsum, int n)
{
    int b = blockIdx.x, t = threadIdx.x;
    int base = b * 1024 + t * 4;
    int s = 0;
    #pragma unroll
    for (int k = 0; k < 4; k++) { int i = base + k; if (i < n) s += deg[i]; }
    #pragma unroll
    for (int off = 32; off >= 1; off >>= 1) s += __shfl_xor(s, off);
    __shared__ int ws[4];
    if ((t & 63) == 0) ws[t >> 6] = s;
    __syncthreads();
    if (t == 0) bsum[b] = ws[0] + ws[1] + ws[2] + ws[3];
}

__global__ void scan_offsets(const int* __restrict__ bsum, int* __restrict__ boff,
                             int nb, int* __restrict__ row_start, int n)
{
    int acc = 0;
    for (int b = 0; b < nb; b++) { boff[b] = acc; acc += bsum[b]; }
    row_start[n] = acc;
}

__global__ __launch_bounds__(256) void scan_write(
    const int* __restrict__ deg, const int* __restrict__ boff,
    int* __restrict__ row_start, int* __restrict__ cursor, int n)
{
    int b = blockIdx.x, t = threadIdx.x, lane = t & 63, w = t >> 6;
    int base = b * 1024 + t * 4;
    int x0, x1, x2, x3;
    x0 = (base + 0 < n) ? deg[base + 0] : 0;
    x1 = (base + 1 < n) ? deg[base + 1] : 0;
    x2 = (base + 2 < n) ? deg[base + 2] : 0;
    x3 = (base + 3 < n) ? deg[base + 3] : 0;
    int tsum = x0 + x1 + x2 + x3;
    int inc = tsum;
    #pragma unroll
    for (int off = 1; off < 64; off <<= 1) {
        int v = __shfl_up(inc, off);
        if (lane >= off) inc += v;
    }
    int texcl = inc - tsum;
    __shared__ int wsum[4];
    if (lane == 63) wsum[w] = inc;
    __syncthreads();
    int wexcl = 0;
    #pragma unroll
    for (int ww = 0; ww < 4; ww++) if (ww < w) wexcl += wsum[ww];
    int basev = boff[b] + wexcl + texcl;
    int p0 = basev;
    int p1 = p0 + x0;
    int p2 = p1 + x1;
    int p3 = p2 + x2;
    if (base + 0 < n) { row_start[base + 0] = p0; cursor[base + 0] = p0; }
    if (base + 1 < n) { row_start[base + 1] = p1; cursor[base + 1] = p1; }
    if (base + 2 < n) { row_start[base + 2] = p2; cursor[base + 2] = p2; }
    if (base + 3 < n) { row_start[base + 3] = p3; cursor[base + 3] = p3; }
}

// ---------------------------------------------------------------------------
// K4: scatter edge ids into CSR slots
// ---------------------------------------------------------------------------
__global__ void scatter_kernel(const int* __restrict__ dst, int* __restrict__ cursor,
                               int* __restrict__ eidx, int E) {
    int i = blockIdx.x * blockDim.x + threadIdx.x;
    if (i < E) {
        int pos = atomicAdd(&cursor[dst[i]], 1);
        eidx[pos] = i;
    }
}

// ---------------------------------------------------------------------------
// K5: FUSED edge-MLP + online-softmax + aggregation. One wave per dst node.
// Walks the node's CSR edge list once:
//   f = leaky_relu(P[src]+Q[dst]+ef@Wf) -> f_out (nontemporal, 2 cols/lane)
//   a = 16-lane reduce of f . wv (head = lane>>4, identical for both layouts)
//   online softmax (m, den) + acc = acc*exp(m-m') + exp(a-m')*h[src] (float4)
// Next-edge loads hand-prefetched (depth 1, named scalars).
// ---------------------------------------------------------------------------
__global__ __launch_bounds__(256) void fused_kernel(
    const int* __restrict__ row_start, const int* __restrict__ eidx,
    const int* __restrict__ src, const float* __restrict__ ef,
    const float* __restrict__ P, const float* __restrict__ Q,
    const float* __restrict__ We, const float* __restrict__ Wa,
    const float* __restrict__ hfeat, float* __restrict__ f_out,
    float* __restrict__ out, int N)
{
    int t = threadIdx.x;
    int lane = t & 63;
    int n = (int)((blockIdx.x * blockDim.x + t) >> 6);
    if (n >= N) return;
    int c0 = lane * 2;

    float4* O4 = (float4*)out;
    int start = row_start[n], end = row_start[n + 1];
    int deg = end - start;
    if (deg == 0) {
        O4[(size_t)n * 64 + lane] = make_float4(0.f, 0.f, 0.f, 0.f);
        return;
    }

    float wf0[7], wf1[7];
    #pragma unroll
    for (int j = 0; j < 7; j++) {
        wf0[j] = We[(size_t)(128 + j) * 128 + c0];
        wf1[j] = We[(size_t)(128 + j) * 128 + c0 + 1];
    }
    int j0 = c0 & 31, j1 = j0 + 1;
    float wv0 = Wa[j0] + Wa[32 + j0] + Wa[64 + j0] + Wa[96 + j0];
    float wv1 = Wa[j1] + Wa[32 + j1] + Wa[64 + j1] + Wa[96 + j1];

    const float2* P2 = (const float2*)P;
    const float2* Q2 = (const float2*)Q;
    const float4* H4 = (const float4*)hfeat;

    float2 qv = Q2[(size_t)n * 64 + lane];

    // preload edge 0
    int e = eidx[start];
    int s = src[e];
    float2 pv = P2[(size_t)s * 64 + lane];
    float4 hv = H4[(size_t)s * 64 + lane];
    const float* ep = ef + (size_t)e * 7;
    float f0 = ep[0], f1 = ep[1], f2 = ep[2], f3 = ep[3], f4 = ep[4], f5 = ep[5], f6 = ep[6];

    float m = -1e30f, den = 0.f;
    float4 acc = make_float4(0.f, 0.f, 0.f, 0.f);

    for (int i = 0; i < deg; i++) {
        // prefetch next edge
        int e2 = 0, s2 = 0;
        float2 pv2 = make_float2(0.f, 0.f);
        float4 hv2 = make_float4(0.f, 0.f, 0.f, 0.f);
        float g0 = 0.f, g1 = 0.f, g2 = 0.f, g3 = 0.f, g4 = 0.f, g5 = 0.f, g6 = 0.f;
        if (i + 1 < deg) {
            e2 = eidx[start + i + 1];
            s2 = src[e2];
            pv2 = P2[(size_t)s2 * 64 + lane];
            hv2 = H4[(size_t)s2 * 64 + lane];
            const float* ep2 = ef + (size_t)e2 * 7;
            g0 = ep2[0]; g1 = ep2[1]; g2 = ep2[2]; g3 = ep2[3]; g4 = ep2[4]; g5 = ep2[5]; g6 = ep2[6];
        }

        // edge MLP (2 cols/lane)
        float a0 = pv.x + qv.x, a1 = pv.y + qv.y;
        a0 = fmaf(f0, wf0[0], a0); a1 = fmaf(f0, wf1[0], a1);
        a0 = fmaf(f1, wf0[1], a0); a1 = fmaf(f1, wf1[1], a1);
        a0 = fmaf(f2, wf0[2], a0); a1 = fmaf(f2, wf1[2], a1);
        a0 = fmaf(f3, wf0[3], a0); a1 = fmaf(f3, wf1[3], a1);
        a0 = fmaf(f4, wf0[4], a0); a1 = fmaf(f4, wf1[4], a1);
        a0 = fmaf(f5, wf0[5], a0); a1 = fmaf(f5, wf1[5], a1);
        a0 = fmaf(f6, wf0[6], a0); a1 = fmaf(f6, wf1[6], a1);
        float v0 = a0 > 0.f ? a0 : NEG_SLOPE * a0;
        float v1 = a1 > 0.f ? a1 : NEG_SLOPE * a1;

        float2 fv = make_float2(v0, v1);
        unsigned long long u;
        __builtin_memcpy(&u, &fv, 8);
        __builtin_nontemporal_store(u, (unsigned long long*)(f_out + (size_t)e * 128 + c0));

        // attention logit: sum over the 16 lanes of this head group
        float p = fmaf(v0, wv0, v1 * wv1);
        p += __shfl_xor(p, 8);
        p += __shfl_xor(p, 4);
        p += __shfl_xor(p, 2);
        p += __shfl_xor(p, 1);

        // online softmax + accumulate
        float nm = fmaxf(m, p);
        float sc = __expf(m - nm);
        float pe = __expf(p - nm);
        den = den * sc + pe;
        acc.x = fmaf(acc.x, sc, pe * hv.x);
        acc.y = fmaf(acc.y, sc, pe * hv.y);
        acc.z = fmaf(acc.z, sc, pe * hv.z);
        acc.w = fmaf(acc.w, sc, pe * hv.w);
        m = nm;

        // rotate prefetched -> current
        e = e2; s = s2; pv = pv2; hv = hv2;
        f0 = g0; f1 = g1; f2 = g2; f3 = g3; f4 = g4; f5 = g5; f6 = g6;
    }

    float r = 1.f / den;
    acc.x *= r; acc.y *= r; acc.z *= r; acc.w *= r;
    O4[(size_t)n * 64 + lane] = acc;
}

// ---------------------------------------------------------------------------
extern "C" void kernel_launch(void* const* d_in, const int* in_sizes, int n_in,
                              void* d_out, int out_size, void* d_ws, size_t ws_size,
                              hipStream_t stream)
{
    const float* nfeats = (const float*)d_in[0];
    const float* efeats = (const float*)d_in[1];
    const int*   src    = (const int*)d_in[2];
    const int*   dst    = (const int*)d_in[3];
    const float* Wn     = (const float*)d_in[4];
    const float* bn     = (const float*)d_in[5];
    const float* We     = (const float*)d_in[6];
    const float* Wa     = (const float*)d_in[7];

    int N = in_sizes[0] / 128;
    int E = in_sizes[2];

    char* ws = (char*)d_ws;
    size_t off = 0;
    float* h_ws  = (float*)(ws + off); off += (size_t)N * 256 * 4;
    float* P     = (float*)(ws + off); off += (size_t)N * 128 * 4;
    float* Qp    = (float*)(ws + off); off += (size_t)N * 128 * 4;
    short* Btg   = (short*)(ws + off); off += (size_t)512 * 128 * 2;
    int* eidx      = (int*)(ws + off); off += (size_t)E * 4;
    int* deg       = (int*)(ws + off); off += (size_t)(N + 1) * 4;
    int* row_start = (int*)(ws + off); off += (size_t)(N + 1) * 4;
    int* cursor    = (int*)(ws + off); off += (size_t)(N + 1) * 4;
    int* bsum      = (int*)(ws + off); off += 1024;
    int* boff      = (int*)(ws + off); off += 1024;

    float* h_out = (float*)d_out;                       // [N, 4, 64]
    float* f_out = (float*)d_out + (size_t)N * 256;     // [E, 4, 32]

    zero_kernel<<<(N + 255) / 256, 256, 0, stream>>>(deg, N);

    bt_prep<<<256, 256, 0, stream>>>(Wn, We, Btg);
    gemm_mfma<<<(N + 127) / 128, 256, 0, stream>>>(nfeats, bn, Btg, h_ws, P, Qp, N);

    count_kernel<<<(E + 255) / 256, 256, 0, stream>>>(dst, deg, E);

    int nb = (N + 1023) / 1024;
    scan_sum<<<nb, 256, 0, stream>>>(deg, bsum, N);
    scan_offsets<<<1, 1, 0, stream>>>(bsum, boff, nb, row_start, N);
    scan_write<<<nb, 256, 0, stream>>>(deg, boff, row_start, cursor, N);

    scatter_kernel<<<(E + 255) / 256, 256, 0, stream>>>(dst, cursor, eidx, E);

    fused_kernel<<<(N + 3) / 4, 256, 0, stream>>>(row_start, eidx, src, efeats,
                                                  P, Qp, We, Wa, h_ws,
                                                  f_out, h_out, N);
}

// Round 5
// 370.570 us; speedup vs baseline: 3.3339x; 1.1136x over previous
//
#include <hip/hip_runtime.h>

#define NEG_SLOPE 0.01f

typedef __attribute__((ext_vector_type(8))) __bf16 bf16x8;
typedef __attribute__((ext_vector_type(4))) float  f32x4;

__device__ __forceinline__ unsigned short f2bf(float x) {
    unsigned u; __builtin_memcpy(&u, &x, 4);
    unsigned r = u + 0x7FFFu + ((u >> 16) & 1u);   // RNE
    return (unsigned short)(r >> 16);
}
__device__ __forceinline__ float bflo(unsigned u) {
    unsigned v = u << 16; float f; __builtin_memcpy(&f, &v, 4); return f;
}
__device__ __forceinline__ float bfhi(unsigned u) {
    unsigned v = u & 0xFFFF0000u; float f; __builtin_memcpy(&f, &v, 4); return f;
}

// ---------------------------------------------------------------------------
// K0: zero the degree array
// ---------------------------------------------------------------------------
__global__ void zero_kernel(int* __restrict__ p, int n) {
    int i = blockIdx.x * blockDim.x + threadIdx.x;
    if (i < n) p[i] = 0;
}

// ---------------------------------------------------------------------------
// K1a: pack all 512 projection columns as B^T bf16 [n=512][k=128].
//   n 0..255   -> W_nodes col n (h);  n 256..383 -> We rows 0..127 (P);
//   n 384..511 -> We rows 135..262 (Q)
// ---------------------------------------------------------------------------
__global__ __launch_bounds__(256) void bt_prep(
    const float* __restrict__ Wn, const float* __restrict__ We,
    short* __restrict__ Btg)
{
    int idx = blockIdx.x * 256 + threadIdx.x;   // 0..65535
    int n = idx >> 7, k = idx & 127;
    float v;
    if (n < 256)      v = Wn[(size_t)k * 256 + n];
    else if (n < 384) v = We[(size_t)k * 128 + (n - 256)];
    else              v = We[(size_t)(135 + k) * 128 + (n - 384)];
    Btg[(size_t)n * 128 + k] = (short)f2bf(v);
}

// ---------------------------------------------------------------------------
// K1b: MFMA projection GEMM: A[N,128](fp32->bf16) @ B[128,512]
// Outputs stored BF16: hbf [N,256] (+bias), Pbf [N,128], Qbf [N,128]
// ---------------------------------------------------------------------------
__global__ __launch_bounds__(256) void gemm_mfma(
    const float* __restrict__ A, const float* __restrict__ bn,
    const short* __restrict__ Btg, unsigned short* __restrict__ hbf,
    unsigned short* __restrict__ Pbf, unsigned short* __restrict__ Qbf, int N)
{
    __shared__ __align__(16) short Al[128 * 136];
    __shared__ __align__(16) short Bl[128 * 136];
    int t = threadIdx.x;
    int row0 = blockIdx.x * 128;

    #pragma unroll
    for (int i = 0; i < 16; i++) {
        int idx = t + i * 256;
        int fr = idx >> 5, fc4 = idx & 31;
        int row = row0 + fr;
        float4 v = make_float4(0.f, 0.f, 0.f, 0.f);
        if (row < N) v = *(const float4*)(A + (size_t)row * 128 + fc4 * 4);
        unsigned long long pk =  (unsigned long long)f2bf(v.x)
                              | ((unsigned long long)f2bf(v.y) << 16)
                              | ((unsigned long long)f2bf(v.z) << 32)
                              | ((unsigned long long)f2bf(v.w) << 48);
        *(unsigned long long*)&Al[fr * 136 + fc4 * 4] = pk;
    }
    __syncthreads();

    int w = t >> 6, l = t & 63;
    int lr = l & 15, lg = l >> 4;

    for (int ct = 0; ct < 4; ct++) {
        if (ct > 0) __syncthreads();
        #pragma unroll
        for (int i = 0; i < 8; i++) {
            int idx = t + i * 256;
            int r = idx >> 4, c8 = idx & 15;
            uint4 v = *(const uint4*)(Btg + (size_t)(ct * 128 + r) * 128 + c8 * 8);
            *(uint4*)&Bl[r * 136 + c8 * 8] = v;
        }
        __syncthreads();

        f32x4 acc[2][8];
        #pragma unroll
        for (int fr = 0; fr < 2; fr++)
            #pragma unroll
            for (int fc = 0; fc < 8; fc++) {
                acc[fr][fc][0] = 0.f; acc[fr][fc][1] = 0.f;
                acc[fr][fc][2] = 0.f; acc[fr][fc][3] = 0.f;
            }

        #pragma unroll
        for (int ks = 0; ks < 4; ks++) {
            int k0 = ks * 32 + lg * 8;
            bf16x8 a0 = *(const bf16x8*)&Al[(w * 32 + lr) * 136 + k0];
            bf16x8 a1 = *(const bf16x8*)&Al[(w * 32 + 16 + lr) * 136 + k0];
            #pragma unroll
            for (int fc = 0; fc < 8; fc++) {
                bf16x8 bb = *(const bf16x8*)&Bl[(fc * 16 + lr) * 136 + k0];
                acc[0][fc] = __builtin_amdgcn_mfma_f32_16x16x32_bf16(a0, bb, acc[0][fc], 0, 0, 0);
                acc[1][fc] = __builtin_amdgcn_mfma_f32_16x16x32_bf16(a1, bb, acc[1][fc], 0, 0, 0);
            }
        }

        #pragma unroll
        for (int fc = 0; fc < 8; fc++) {
            int col = fc * 16 + lr;
            float bias = (ct < 2) ? bn[ct * 128 + col] : 0.f;
            #pragma unroll
            for (int fr = 0; fr < 2; fr++) {
                #pragma unroll
                for (int b = 0; b < 4; b++) {
                    int row = row0 + w * 32 + fr * 16 + lg * 4 + b;
                    if (row >= N) continue;
                    unsigned short bv = f2bf(acc[fr][fc][b] + bias);
                    if (ct < 2)       hbf[(size_t)row * 256 + ct * 128 + col] = bv;
                    else if (ct == 2) Pbf[(size_t)row * 128 + col] = bv;
                    else              Qbf[(size_t)row * 128 + col] = bv;
                }
            }
        }
    }
}

// ---------------------------------------------------------------------------
// K2: per-destination degree count
// ---------------------------------------------------------------------------
__global__ void count_kernel(const int* __restrict__ dst, int* __restrict__ deg, int E) {
    int i = blockIdx.x * blockDim.x + threadIdx.x;
    if (i < E) atomicAdd(&deg[dst[i]], 1);
}

// ---------------------------------------------------------------------------
// K3a/b/c: multi-block exclusive scan of deg -> row_start, cursor
// ---------------------------------------------------------------------------
__global__ __launch_bounds__(256) void scan_sum(
    const int* __restrict__ deg, int* __restrict__ bsum, int n)
{
    int b = blockIdx.x, t = threadIdx.x;
    int base = b * 1024 + t * 4;
    int s = 0;
    #pragma unroll
    for (int k = 0; k < 4; k++) { int i = base + k; if (i < n) s += deg[i]; }
    #pragma unroll
    for (int off = 32; off >= 1; off >>= 1) s += __shfl_xor(s, off);
    __shared__ int ws[4];
    if ((t & 63) == 0) ws[t >> 6] = s;
    __syncthreads();
    if (t == 0) bsum[b] = ws[0] + ws[1] + ws[2] + ws[3];
}

__global__ void scan_offsets(const int* __restrict__ bsum, int* __restrict__ boff,
                             int nb, int* __restrict__ row_start, int n)
{
    int acc = 0;
    for (int b = 0; b < nb; b++) { boff[b] = acc; acc += bsum[b]; }
    row_start[n] = acc;
}

__global__ __launch_bounds__(256) void scan_write(
    const int* __restrict__ deg, const int* __restrict__ boff,
    int* __restrict__ row_start, int* __restrict__ cursor, int n)
{
    int b = blockIdx.x, t = threadIdx.x, lane = t & 63, w = t >> 6;
    int base = b * 1024 + t * 4;
    int x0, x1, x2, x3;
    x0 = (base + 0 < n) ? deg[base + 0] : 0;
    x1 = (base + 1 < n) ? deg[base + 1] : 0;
    x2 = (base + 2 < n) ? deg[base + 2] : 0;
    x3 = (base + 3 < n) ? deg[base + 3] : 0;
    int tsum = x0 + x1 + x2 + x3;
    int inc = tsum;
    #pragma unroll
    for (int off = 1; off < 64; off <<= 1) {
        int v = __shfl_up(inc, off);
        if (lane >= off) inc += v;
    }
    int texcl = inc - tsum;
    __shared__ int wsum[4];
    if (lane == 63) wsum[w] = inc;
    __syncthreads();
    int wexcl = 0;
    #pragma unroll
    for (int ww = 0; ww < 4; ww++) if (ww < w) wexcl += wsum[ww];
    int basev = boff[b] + wexcl + texcl;
    int p0 = basev;
    int p1 = p0 + x0;
    int p2 = p1 + x1;
    int p3 = p2 + x2;
    if (base + 0 < n) { row_start[base + 0] = p0; cursor[base + 0] = p0; }
    if (base + 1 < n) { row_start[base + 1] = p1; cursor[base + 1] = p1; }
    if (base + 2 < n) { row_start[base + 2] = p2; cursor[base + 2] = p2; }
    if (base + 3 < n) { row_start[base + 3] = p3; cursor[base + 3] = p3; }
}

// ---------------------------------------------------------------------------
// K4: scatter edge ids into CSR slots
// ---------------------------------------------------------------------------
__global__ void scatter_kernel(const int* __restrict__ dst, int* __restrict__ cursor,
                               int* __restrict__ eidx, int E) {
    int i = blockIdx.x * blockDim.x + threadIdx.x;
    if (i < E) {
        int pos = atomicAdd(&cursor[dst[i]], 1);
        eidx[pos] = i;
    }
}

// ---------------------------------------------------------------------------
// K5: FUSED edge-MLP + online-softmax + aggregation. One wave per dst node.
// All per-node gathers (P, Q, h) in bf16: 768 B/edge instead of 1536.
// ---------------------------------------------------------------------------
__global__ __launch_bounds__(256) void fused_kernel(
    const int* __restrict__ row_start, const int* __restrict__ eidx,
    const int* __restrict__ src, const float* __restrict__ ef,
    const unsigned short* __restrict__ Pbf, const unsigned short* __restrict__ Qbf,
    const unsigned short* __restrict__ hbf,
    const float* __restrict__ We, const float* __restrict__ Wa,
    float* __restrict__ f_out, float* __restrict__ out, int N)
{
    int t = threadIdx.x;
    int lane = t & 63;
    int n = (int)((blockIdx.x * blockDim.x + t) >> 6);
    if (n >= N) return;
    int c0 = lane * 2;

    float4* O4 = (float4*)out;
    int start = row_start[n], end = row_start[n + 1];
    int deg = end - start;
    if (deg == 0) {
        O4[(size_t)n * 64 + lane] = make_float4(0.f, 0.f, 0.f, 0.f);
        return;
    }

    float wf0[7], wf1[7];
    #pragma unroll
    for (int j = 0; j < 7; j++) {
        wf0[j] = We[(size_t)(128 + j) * 128 + c0];
        wf1[j] = We[(size_t)(128 + j) * 128 + c0 + 1];
    }
    int j0 = c0 & 31, j1 = j0 + 1;
    float wv0 = Wa[j0] + Wa[32 + j0] + Wa[64 + j0] + Wa[96 + j0];
    float wv1 = Wa[j1] + Wa[32 + j1] + Wa[64 + j1] + Wa[96 + j1];

    const unsigned* P1 = (const unsigned*)Pbf;   // 2 bf16 cols per lane
    const unsigned* Q1 = (const unsigned*)Qbf;
    const uint2*    H2 = (const uint2*)hbf;      // 4 bf16 cols per lane

    unsigned qu = Q1[(size_t)n * 64 + lane];
    float q0 = bflo(qu), q1 = bfhi(qu);

    // preload edge 0
    int e = eidx[start];
    int s = src[e];
    unsigned pu = P1[(size_t)s * 64 + lane];
    uint2 hu = H2[(size_t)s * 64 + lane];
    const float* ep = ef + (size_t)e * 7;
    float f0 = ep[0], f1 = ep[1], f2 = ep[2], f3 = ep[3], f4 = ep[4], f5 = ep[5], f6 = ep[6];

    float m = -1e30f, den = 0.f;
    float4 acc = make_float4(0.f, 0.f, 0.f, 0.f);

    for (int i = 0; i < deg; i++) {
        // prefetch next edge
        int e2 = 0, s2 = 0;
        unsigned pu2 = 0;
        uint2 hu2 = make_uint2(0u, 0u);
        float g0 = 0.f, g1 = 0.f, g2 = 0.f, g3 = 0.f, g4 = 0.f, g5 = 0.f, g6 = 0.f;
        if (i + 1 < deg) {
            e2 = eidx[start + i + 1];
            s2 = src[e2];
            pu2 = P1[(size_t)s2 * 64 + lane];
            hu2 = H2[(size_t)s2 * 64 + lane];
            const float* ep2 = ef + (size_t)e2 * 7;
            g0 = ep2[0]; g1 = ep2[1]; g2 = ep2[2]; g3 = ep2[3]; g4 = ep2[4]; g5 = ep2[5]; g6 = ep2[6];
        }

        // edge MLP (2 cols/lane)
        float a0 = bflo(pu) + q0, a1 = bfhi(pu) + q1;
        a0 = fmaf(f0, wf0[0], a0); a1 = fmaf(f0, wf1[0], a1);
        a0 = fmaf(f1, wf0[1], a0); a1 = fmaf(f1, wf1[1], a1);
        a0 = fmaf(f2, wf0[2], a0); a1 = fmaf(f2, wf1[2], a1);
        a0 = fmaf(f3, wf0[3], a0); a1 = fmaf(f3, wf1[3], a1);
        a0 = fmaf(f4, wf0[4], a0); a1 = fmaf(f4, wf1[4], a1);
        a0 = fmaf(f5, wf0[5], a0); a1 = fmaf(f5, wf1[5], a1);
        a0 = fmaf(f6, wf0[6], a0); a1 = fmaf(f6, wf1[6], a1);
        float v0 = a0 > 0.f ? a0 : NEG_SLOPE * a0;
        float v1 = a1 > 0.f ? a1 : NEG_SLOPE * a1;

        float2 fv = make_float2(v0, v1);
        unsigned long long u;
        __builtin_memcpy(&u, &fv, 8);
        __builtin_nontemporal_store(u, (unsigned long long*)(f_out + (size_t)e * 128 + c0));

        // attention logit: reduce over the 16 lanes of this head group
        float p = fmaf(v0, wv0, v1 * wv1);
        p += __shfl_xor(p, 8);
        p += __shfl_xor(p, 4);
        p += __shfl_xor(p, 2);
        p += __shfl_xor(p, 1);

        // online softmax + accumulate (4 h-cols per lane, bf16 -> fp32)
        float nm = fmaxf(m, p);
        float sc = __expf(m - nm);
        float pe = __expf(p - nm);
        den = den * sc + pe;
        float hx0 = bflo(hu.x), hx1 = bfhi(hu.x);
        float hx2 = bflo(hu.y), hx3 = bfhi(hu.y);
        acc.x = fmaf(acc.x, sc, pe * hx0);
        acc.y = fmaf(acc.y, sc, pe * hx1);
        acc.z = fmaf(acc.z, sc, pe * hx2);
        acc.w = fmaf(acc.w, sc, pe * hx3);
        m = nm;

        // rotate prefetched -> current
        e = e2; s = s2; pu = pu2; hu = hu2;
        f0 = g0; f1 = g1; f2 = g2; f3 = g3; f4 = g4; f5 = g5; f6 = g6;
    }

    float r = 1.f / den;
    acc.x *= r; acc.y *= r; acc.z *= r; acc.w *= r;
    O4[(size_t)n * 64 + lane] = acc;
}

// ---------------------------------------------------------------------------
extern "C" void kernel_launch(void* const* d_in, const int* in_sizes, int n_in,
                              void* d_out, int out_size, void* d_ws, size_t ws_size,
                              hipStream_t stream)
{
    const float* nfeats = (const float*)d_in[0];
    const float* efeats = (const float*)d_in[1];
    const int*   src    = (const int*)d_in[2];
    const int*   dst    = (const int*)d_in[3];
    const float* Wn     = (const float*)d_in[4];
    const float* bn     = (const float*)d_in[5];
    const float* We     = (const float*)d_in[6];
    const float* Wa     = (const float*)d_in[7];

    int N = in_sizes[0] / 128;
    int E = in_sizes[2];

    char* ws = (char*)d_ws;
    size_t off = 0;
    unsigned short* hbf = (unsigned short*)(ws + off); off += (size_t)N * 256 * 2;
    unsigned short* Pbf = (unsigned short*)(ws + off); off += (size_t)N * 128 * 2;
    unsigned short* Qbf = (unsigned short*)(ws + off); off += (size_t)N * 128 * 2;
    short* Btg   = (short*)(ws + off); off += (size_t)512 * 128 * 2;
    int* eidx      = (int*)(ws + off); off += (size_t)E * 4;
    int* deg       = (int*)(ws + off); off += (size_t)(N + 1) * 4;
    int* row_start = (int*)(ws + off); off += (size_t)(N + 1) * 4;
    int* cursor    = (int*)(ws + off); off += (size_t)(N + 1) * 4;
    int* bsum      = (int*)(ws + off); off += 1024;
    int* boff      = (int*)(ws + off); off += 1024;

    float* h_out = (float*)d_out;                       // [N, 4, 64]
    float* f_out = (float*)d_out + (size_t)N * 256;     // [E, 4, 32]

    zero_kernel<<<(N + 255) / 256, 256, 0, stream>>>(deg, N);

    bt_prep<<<256, 256, 0, stream>>>(Wn, We, Btg);
    gemm_mfma<<<(N + 127) / 128, 256, 0, stream>>>(nfeats, bn, Btg, hbf, Pbf, Qbf, N);

    count_kernel<<<(E + 255) / 256, 256, 0, stream>>>(dst, deg, E);

    int nb = (N + 1023) / 1024;
    scan_sum<<<nb, 256, 0, stream>>>(deg, bsum, N);
    scan_offsets<<<1, 1, 0, stream>>>(bsum, boff, nb, row_start, N);
    scan_write<<<nb, 256, 0, stream>>>(deg, boff, row_start, cursor, N);

    scatter_kernel<<<(E + 255) / 256, 256, 0, stream>>>(dst, cursor, eidx, E);

    fused_kernel<<<(N + 3) / 4, 256, 0, stream>>>(row_start, eidx, src, efeats,
                                                  Pbf, Qbf, hbf, We, Wa,
                                                  f_out, h_out, N);
}

// Round 6
// 333.868 us; speedup vs baseline: 3.7003x; 1.1099x over previous
//
#include <hip/hip_runtime.h>

#define NEG_SLOPE 0.01f

typedef __attribute__((ext_vector_type(8))) __bf16 bf16x8;
typedef __attribute__((ext_vector_type(4))) float  f32x4;

__device__ __forceinline__ unsigned short f2bf(float x) {
    unsigned u; __builtin_memcpy(&u, &x, 4);
    unsigned r = u + 0x7FFFu + ((u >> 16) & 1u);   // RNE
    return (unsigned short)(r >> 16);
}
__device__ __forceinline__ float bflo(unsigned u) {
    unsigned v = u << 16; float f; __builtin_memcpy(&f, &v, 4); return f;
}
__device__ __forceinline__ float bfhi(unsigned u) {
    unsigned v = u & 0xFFFF0000u; float f; __builtin_memcpy(&f, &v, 4); return f;
}

// ---------------------------------------------------------------------------
// K0: zero the degree array
// ---------------------------------------------------------------------------
__global__ void zero_kernel(int* __restrict__ p, int n) {
    int i = blockIdx.x * blockDim.x + threadIdx.x;
    if (i < n) p[i] = 0;
}

// ---------------------------------------------------------------------------
// K1a: pack all 512 projection columns as B^T bf16 [n=512][k=128].
// ---------------------------------------------------------------------------
__global__ __launch_bounds__(256) void bt_prep(
    const float* __restrict__ Wn, const float* __restrict__ We,
    short* __restrict__ Btg)
{
    int idx = blockIdx.x * 256 + threadIdx.x;   // 0..65535
    int n = idx >> 7, k = idx & 127;
    float v;
    if (n < 256)      v = Wn[(size_t)k * 256 + n];
    else if (n < 384) v = We[(size_t)k * 128 + (n - 256)];
    else              v = We[(size_t)(135 + k) * 128 + (n - 384)];
    Btg[(size_t)n * 128 + k] = (short)f2bf(v);
}

// ---------------------------------------------------------------------------
// K1b: MFMA projection GEMM: A[N,128](fp32->bf16) @ B[128,512]
// Outputs stored BF16: hbf [N,256] (+bias), Pbf [N,128], Qbf [N,128]
// ---------------------------------------------------------------------------
__global__ __launch_bounds__(256) void gemm_mfma(
    const float* __restrict__ A, const float* __restrict__ bn,
    const short* __restrict__ Btg, unsigned short* __restrict__ hbf,
    unsigned short* __restrict__ Pbf, unsigned short* __restrict__ Qbf, int N)
{
    __shared__ __align__(16) short Al[128 * 136];
    __shared__ __align__(16) short Bl[128 * 136];
    int t = threadIdx.x;
    int row0 = blockIdx.x * 128;

    #pragma unroll
    for (int i = 0; i < 16; i++) {
        int idx = t + i * 256;
        int fr = idx >> 5, fc4 = idx & 31;
        int row = row0 + fr;
        float4 v = make_float4(0.f, 0.f, 0.f, 0.f);
        if (row < N) v = *(const float4*)(A + (size_t)row * 128 + fc4 * 4);
        unsigned long long pk =  (unsigned long long)f2bf(v.x)
                              | ((unsigned long long)f2bf(v.y) << 16)
                              | ((unsigned long long)f2bf(v.z) << 32)
                              | ((unsigned long long)f2bf(v.w) << 48);
        *(unsigned long long*)&Al[fr * 136 + fc4 * 4] = pk;
    }
    __syncthreads();

    int w = t >> 6, l = t & 63;
    int lr = l & 15, lg = l >> 4;

    for (int ct = 0; ct < 4; ct++) {
        if (ct > 0) __syncthreads();
        #pragma unroll
        for (int i = 0; i < 8; i++) {
            int idx = t + i * 256;
            int r = idx >> 4, c8 = idx & 15;
            uint4 v = *(const uint4*)(Btg + (size_t)(ct * 128 + r) * 128 + c8 * 8);
            *(uint4*)&Bl[r * 136 + c8 * 8] = v;
        }
        __syncthreads();

        f32x4 acc[2][8];
        #pragma unroll
        for (int fr = 0; fr < 2; fr++)
            #pragma unroll
            for (int fc = 0; fc < 8; fc++) {
                acc[fr][fc][0] = 0.f; acc[fr][fc][1] = 0.f;
                acc[fr][fc][2] = 0.f; acc[fr][fc][3] = 0.f;
            }

        #pragma unroll
        for (int ks = 0; ks < 4; ks++) {
            int k0 = ks * 32 + lg * 8;
            bf16x8 a0 = *(const bf16x8*)&Al[(w * 32 + lr) * 136 + k0];
            bf16x8 a1 = *(const bf16x8*)&Al[(w * 32 + 16 + lr) * 136 + k0];
            #pragma unroll
            for (int fc = 0; fc < 8; fc++) {
                bf16x8 bb = *(const bf16x8*)&Bl[(fc * 16 + lr) * 136 + k0];
                acc[0][fc] = __builtin_amdgcn_mfma_f32_16x16x32_bf16(a0, bb, acc[0][fc], 0, 0, 0);
                acc[1][fc] = __builtin_amdgcn_mfma_f32_16x16x32_bf16(a1, bb, acc[1][fc], 0, 0, 0);
            }
        }

        #pragma unroll
        for (int fc = 0; fc < 8; fc++) {
            int col = fc * 16 + lr;
            float bias = (ct < 2) ? bn[ct * 128 + col] : 0.f;
            #pragma unroll
            for (int fr = 0; fr < 2; fr++) {
                #pragma unroll
                for (int b = 0; b < 4; b++) {
                    int row = row0 + w * 32 + fr * 16 + lg * 4 + b;
                    if (row >= N) continue;
                    unsigned short bv = f2bf(acc[fr][fc][b] + bias);
                    if (ct < 2)       hbf[(size_t)row * 256 + ct * 128 + col] = bv;
                    else if (ct == 2) Pbf[(size_t)row * 128 + col] = bv;
                    else              Qbf[(size_t)row * 128 + col] = bv;
                }
            }
        }
    }
}

// ---------------------------------------------------------------------------
// K2: per-destination degree count
// ---------------------------------------------------------------------------
__global__ void count_kernel(const int* __restrict__ dst, int* __restrict__ deg, int E) {
    int i = blockIdx.x * blockDim.x + threadIdx.x;
    if (i < E) atomicAdd(&deg[dst[i]], 1);
}

// ---------------------------------------------------------------------------
// K3a/b/c: multi-block exclusive scan of deg -> row_start, cursor
// ---------------------------------------------------------------------------
__global__ __launch_bounds__(256) void scan_sum(
    const int* __restrict__ deg, int* __restrict__ bsum, int n)
{
    int b = blockIdx.x, t = threadIdx.x;
    int base = b * 1024 + t * 4;
    int s = 0;
    #pragma unroll
    for (int k = 0; k < 4; k++) { int i = base + k; if (i < n) s += deg[i]; }
    #pragma unroll
    for (int off = 32; off >= 1; off >>= 1) s += __shfl_xor(s, off);
    __shared__ int ws[4];
    if ((t & 63) == 0) ws[t >> 6] = s;
    __syncthreads();
    if (t == 0) bsum[b] = ws[0] + ws[1] + ws[2] + ws[3];
}

__global__ void scan_offsets(const int* __restrict__ bsum, int* __restrict__ boff,
                             int nb, int* __restrict__ row_start, int n)
{
    int acc = 0;
    for (int b = 0; b < nb; b++) { boff[b] = acc; acc += bsum[b]; }
    row_start[n] = acc;
}

__global__ __launch_bounds__(256) void scan_write(
    const int* __restrict__ deg, const int* __restrict__ boff,
    int* __restrict__ row_start, int* __restrict__ cursor, int n)
{
    int b = blockIdx.x, t = threadIdx.x, lane = t & 63, w = t >> 6;
    int base = b * 1024 + t * 4;
    int x0, x1, x2, x3;
    x0 = (base + 0 < n) ? deg[base + 0] : 0;
    x1 = (base + 1 < n) ? deg[base + 1] : 0;
    x2 = (base + 2 < n) ? deg[base + 2] : 0;
    x3 = (base + 3 < n) ? deg[base + 3] : 0;
    int tsum = x0 + x1 + x2 + x3;
    int inc = tsum;
    #pragma unroll
    for (int off = 1; off < 64; off <<= 1) {
        int v = __shfl_up(inc, off);
        if (lane >= off) inc += v;
    }
    int texcl = inc - tsum;
    __shared__ int wsum[4];
    if (lane == 63) wsum[w] = inc;
    __syncthreads();
    int wexcl = 0;
    #pragma unroll
    for (int ww = 0; ww < 4; ww++) if (ww < w) wexcl += wsum[ww];
    int basev = boff[b] + wexcl + texcl;
    int p0 = basev;
    int p1 = p0 + x0;
    int p2 = p1 + x1;
    int p3 = p2 + x2;
    if (base + 0 < n) { row_start[base + 0] = p0; cursor[base + 0] = p0; }
    if (base + 1 < n) { row_start[base + 1] = p1; cursor[base + 1] = p1; }
    if (base + 2 < n) { row_start[base + 2] = p2; cursor[base + 2] = p2; }
    if (base + 3 < n) { row_start[base + 3] = p3; cursor[base + 3] = p3; }
}

// ---------------------------------------------------------------------------
// K4: scatter edge ids AND src node ids into CSR slots
// ---------------------------------------------------------------------------
__global__ void scatter_kernel(const int* __restrict__ dst, const int* __restrict__ src,
                               int* __restrict__ cursor,
                               int* __restrict__ eidx, int* __restrict__ ssrc, int E) {
    int i = blockIdx.x * blockDim.x + threadIdx.x;
    if (i < E) {
        int pos = atomicAdd(&cursor[dst[i]], 1);
        eidx[pos] = i;
        ssrc[pos] = src[i];
    }
}

// ---------------------------------------------------------------------------
// K5: FUSED edge-MLP + online-softmax + aggregation. One wave per dst node.
// Dual-stream unroll-2 (independent softmax states A/B, merged at end),
// depth-1 prefetch per stream -> 4 gathers in flight. Wave-uniform e/s/ef
// scalarized via readfirstlane (SGPRs, scalar loads).
// ---------------------------------------------------------------------------
__global__ __launch_bounds__(256) void fused_kernel(
    const int* __restrict__ row_start, const int* __restrict__ eidx,
    const int* __restrict__ ssrc, const float* __restrict__ ef,
    const unsigned short* __restrict__ Pbf, const unsigned short* __restrict__ Qbf,
    const unsigned short* __restrict__ hbf,
    const float* __restrict__ We, const float* __restrict__ Wa,
    float* __restrict__ f_out, float* __restrict__ out, int N)
{
    int t = threadIdx.x;
    int lane = t & 63;
    int n = (int)((blockIdx.x * blockDim.x + t) >> 6);
    if (n >= N) return;
    int c0 = lane * 2;

    float4* O4 = (float4*)out;
    int nu = __builtin_amdgcn_readfirstlane(n);
    int start = row_start[nu];
    int deg   = row_start[nu + 1] - start;
    if (deg == 0) {
        O4[(size_t)n * 64 + lane] = make_float4(0.f, 0.f, 0.f, 0.f);
        return;
    }

    float wf0[7], wf1[7];
    #pragma unroll
    for (int j = 0; j < 7; j++) {
        wf0[j] = We[(size_t)(128 + j) * 128 + c0];
        wf1[j] = We[(size_t)(128 + j) * 128 + c0 + 1];
    }
    int j0 = c0 & 31, j1 = j0 + 1;
    float wv0 = Wa[j0] + Wa[32 + j0] + Wa[64 + j0] + Wa[96 + j0];
    float wv1 = Wa[j1] + Wa[32 + j1] + Wa[64 + j1] + Wa[96 + j1];

    const unsigned* P1 = (const unsigned*)Pbf;   // 2 bf16 cols per lane
    const uint2*    H2 = (const uint2*)hbf;      // 4 bf16 cols per lane

    unsigned qu = ((const unsigned*)Qbf)[(size_t)n * 64 + lane];
    float q0 = bflo(qu), q1 = bfhi(qu);

    // load edge at CSR-local position pos (uniform) into named regs
    #define LOADE(pos, e_, pu_, hu_, F0,F1,F2,F3,F4,F5,F6) {            \
        int p_ = start + (pos);                                          \
        e_ = __builtin_amdgcn_readfirstlane(eidx[p_]);                   \
        int s_ = __builtin_amdgcn_readfirstlane(ssrc[p_]);               \
        pu_ = P1[(size_t)s_ * 64 + lane];                                \
        hu_ = H2[(size_t)s_ * 64 + lane];                                \
        const float* ep_ = ef + (size_t)e_ * 7;                          \
        F0 = ep_[0]; F1 = ep_[1]; F2 = ep_[2]; F3 = ep_[3];              \
        F4 = ep_[4]; F5 = ep_[5]; F6 = ep_[6]; }

    // full per-edge pipeline: MLP -> f_out store -> logit reduce -> online SM
    #define PROC(e_, pu_, hu_, F0,F1,F2,F3,F4,F5,F6, m_, d_, ac_) {     \
        float a0 = bflo(pu_) + q0, a1 = bfhi(pu_) + q1;                  \
        a0 = fmaf(F0, wf0[0], a0); a1 = fmaf(F0, wf1[0], a1);            \
        a0 = fmaf(F1, wf0[1], a0); a1 = fmaf(F1, wf1[1], a1);            \
        a0 = fmaf(F2, wf0[2], a0); a1 = fmaf(F2, wf1[2], a1);            \
        a0 = fmaf(F3, wf0[3], a0); a1 = fmaf(F3, wf1[3], a1);            \
        a0 = fmaf(F4, wf0[4], a0); a1 = fmaf(F4, wf1[4], a1);            \
        a0 = fmaf(F5, wf0[5], a0); a1 = fmaf(F5, wf1[5], a1);            \
        a0 = fmaf(F6, wf0[6], a0); a1 = fmaf(F6, wf1[6], a1);            \
        float v0 = a0 > 0.f ? a0 : NEG_SLOPE * a0;                       \
        float v1 = a1 > 0.f ? a1 : NEG_SLOPE * a1;                       \
        float2 fv_ = make_float2(v0, v1);                                \
        unsigned long long u_;                                           \
        __builtin_memcpy(&u_, &fv_, 8);                                  \
        __builtin_nontemporal_store(u_,                                  \
            (unsigned long long*)(f_out + (size_t)e_ * 128 + c0));       \
        float p_ = fmaf(v0, wv0, v1 * wv1);                              \
        p_ += __shfl_xor(p_, 8);                                         \
        p_ += __shfl_xor(p_, 4);                                         \
        p_ += __shfl_xor(p_, 2);                                         \
        p_ += __shfl_xor(p_, 1);                                         \
        float nm_ = fmaxf(m_, p_);                                       \
        float sc_ = __expf(m_ - nm_);                                    \
        float pe_ = __expf(p_ - nm_);                                    \
        d_ = d_ * sc_ + pe_;                                             \
        float hx0 = bflo(hu_.x), hx1 = bfhi(hu_.x);                      \
        float hx2 = bflo(hu_.y), hx3 = bfhi(hu_.y);                      \
        ac_.x = fmaf(ac_.x, sc_, pe_ * hx0);                             \
        ac_.y = fmaf(ac_.y, sc_, pe_ * hx1);                             \
        ac_.z = fmaf(ac_.z, sc_, pe_ * hx2);                             \
        ac_.w = fmaf(ac_.w, sc_, pe_ * hx3);                             \
        m_ = nm_; }

    float mA = -1e30f, dA = 0.f; float4 aA = make_float4(0.f, 0.f, 0.f, 0.f);
    float mB = -1e30f, dB = 0.f; float4 aB = make_float4(0.f, 0.f, 0.f, 0.f);

    int eA = 0; unsigned puA = 0; uint2 huA = make_uint2(0u, 0u);
    float fA0 = 0.f, fA1 = 0.f, fA2 = 0.f, fA3 = 0.f, fA4 = 0.f, fA5 = 0.f, fA6 = 0.f;
    int eB = 0; unsigned puB = 0; uint2 huB = make_uint2(0u, 0u);
    float fB0 = 0.f, fB1 = 0.f, fB2 = 0.f, fB3 = 0.f, fB4 = 0.f, fB5 = 0.f, fB6 = 0.f;

    LOADE(0, eA, puA, huA, fA0, fA1, fA2, fA3, fA4, fA5, fA6);
    if (deg > 1) LOADE(1, eB, puB, huB, fB0, fB1, fB2, fB3, fB4, fB5, fB6);

    for (int k = 0;; k++) {
        int pB = 2 * k + 1;
        int nA = 2 * k + 2, nB = 2 * k + 3;
        int eA2 = 0; unsigned puA2 = 0; uint2 huA2 = make_uint2(0u, 0u);
        float gA0 = 0.f, gA1 = 0.f, gA2 = 0.f, gA3 = 0.f, gA4 = 0.f, gA5 = 0.f, gA6 = 0.f;
        int eB2 = 0; unsigned puB2 = 0; uint2 huB2 = make_uint2(0u, 0u);
        float gB0 = 0.f, gB1 = 0.f, gB2 = 0.f, gB3 = 0.f, gB4 = 0.f, gB5 = 0.f, gB6 = 0.f;
        if (nA < deg) LOADE(nA, eA2, puA2, huA2, gA0, gA1, gA2, gA3, gA4, gA5, gA6);
        if (nB < deg) LOADE(nB, eB2, puB2, huB2, gB0, gB1, gB2, gB3, gB4, gB5, gB6);

        PROC(eA, puA, huA, fA0, fA1, fA2, fA3, fA4, fA5, fA6, mA, dA, aA);
        if (pB < deg)
            PROC(eB, puB, huB, fB0, fB1, fB2, fB3, fB4, fB5, fB6, mB, dB, aB);

        if (nA >= deg) break;
        eA = eA2; puA = puA2; huA = huA2;
        fA0 = gA0; fA1 = gA1; fA2 = gA2; fA3 = gA3; fA4 = gA4; fA5 = gA5; fA6 = gA6;
        eB = eB2; puB = puB2; huB = huB2;
        fB0 = gB0; fB1 = gB1; fB2 = gB2; fB3 = gB3; fB4 = gB4; fB5 = gB5; fB6 = gB6;
    }

    // merge the two softmax states (scB -> 0 when stream B is empty)
    float nm = fmaxf(mA, mB);
    float scA = __expf(mA - nm), scB = __expf(mB - nm);
    float den = dA * scA + dB * scB;
    float r = 1.f / den;
    float4 acc;
    acc.x = (aA.x * scA + aB.x * scB) * r;
    acc.y = (aA.y * scA + aB.y * scB) * r;
    acc.z = (aA.z * scA + aB.z * scB) * r;
    acc.w = (aA.w * scA + aB.w * scB) * r;
    O4[(size_t)n * 64 + lane] = acc;

    #undef LOADE
    #undef PROC
}

// ---------------------------------------------------------------------------
extern "C" void kernel_launch(void* const* d_in, const int* in_sizes, int n_in,
                              void* d_out, int out_size, void* d_ws, size_t ws_size,
                              hipStream_t stream)
{
    const float* nfeats = (const float*)d_in[0];
    const float* efeats = (const float*)d_in[1];
    const int*   src    = (const int*)d_in[2];
    const int*   dst    = (const int*)d_in[3];
    const float* Wn     = (const float*)d_in[4];
    const float* bn     = (const float*)d_in[5];
    const float* We     = (const float*)d_in[6];
    const float* Wa     = (const float*)d_in[7];

    int N = in_sizes[0] / 128;
    int E = in_sizes[2];

    char* ws = (char*)d_ws;
    size_t off = 0;
    unsigned short* hbf = (unsigned short*)(ws + off); off += (size_t)N * 256 * 2;
    unsigned short* Pbf = (unsigned short*)(ws + off); off += (size_t)N * 128 * 2;
    unsigned short* Qbf = (unsigned short*)(ws + off); off += (size_t)N * 128 * 2;
    short* Btg   = (short*)(ws + off); off += (size_t)512 * 128 * 2;
    int* eidx      = (int*)(ws + off); off += (size_t)E * 4;
    int* ssrc      = (int*)(ws + off); off += (size_t)E * 4;
    int* deg       = (int*)(ws + off); off += (size_t)(N + 1) * 4;
    int* row_start = (int*)(ws + off); off += (size_t)(N + 1) * 4;
    int* cursor    = (int*)(ws + off); off += (size_t)(N + 1) * 4;
    int* bsum      = (int*)(ws + off); off += 1024;
    int* boff      = (int*)(ws + off); off += 1024;

    float* h_out = (float*)d_out;                       // [N, 4, 64]
    float* f_out = (float*)d_out + (size_t)N * 256;     // [E, 4, 32]

    zero_kernel<<<(N + 255) / 256, 256, 0, stream>>>(deg, N);

    bt_prep<<<256, 256, 0, stream>>>(Wn, We, Btg);
    gemm_mfma<<<(N + 127) / 128, 256, 0, stream>>>(nfeats, bn, Btg, hbf, Pbf, Qbf, N);

    count_kernel<<<(E + 255) / 256, 256, 0, stream>>>(dst, deg, E);

    int nb = (N + 1023) / 1024;
    scan_sum<<<nb, 256, 0, stream>>>(deg, bsum, N);
    scan_offsets<<<1, 1, 0, stream>>>(bsum, boff, nb, row_start, N);
    scan_write<<<nb, 256, 0, stream>>>(deg, boff, row_start, cursor, N);

    scatter_kernel<<<(E + 255) / 256, 256, 0, stream>>>(dst, src, cursor, eidx, ssrc, E);

    fused_kernel<<<(N + 3) / 4, 256, 0, stream>>>(row_start, eidx, ssrc, efeats,
                                                  Pbf, Qbf, hbf, We, Wa,
                                                  f_out, h_out, N);
}

// Round 7
// 327.270 us; speedup vs baseline: 3.7749x; 1.0202x over previous
//
#include <hip/hip_runtime.h>

#define NEG_SLOPE 0.01f

typedef __attribute__((ext_vector_type(8))) __bf16 bf16x8;
typedef __attribute__((ext_vector_type(4))) float  f32x4;

__device__ __forceinline__ unsigned short f2bf(float x) {
    unsigned u; __builtin_memcpy(&u, &x, 4);
    unsigned r = u + 0x7FFFu + ((u >> 16) & 1u);   // RNE
    return (unsigned short)(r >> 16);
}
__device__ __forceinline__ float bflo(unsigned u) {
    unsigned v = u << 16; float f; __builtin_memcpy(&f, &v, 4); return f;
}
__device__ __forceinline__ float bfhi(unsigned u) {
    unsigned v = u & 0xFFFF0000u; float f; __builtin_memcpy(&f, &v, 4); return f;
}

// ---------------------------------------------------------------------------
// K0: zero the degree array
// ---------------------------------------------------------------------------
__global__ void zero_kernel(int* __restrict__ p, int n) {
    int i = blockIdx.x * blockDim.x + threadIdx.x;
    if (i < n) p[i] = 0;
}

// ---------------------------------------------------------------------------
// K1a: pack all 512 projection columns as B^T bf16 [n=512][k=128].
// ---------------------------------------------------------------------------
__global__ __launch_bounds__(256) void bt_prep(
    const float* __restrict__ Wn, const float* __restrict__ We,
    short* __restrict__ Btg)
{
    int idx = blockIdx.x * 256 + threadIdx.x;   // 0..65535
    int n = idx >> 7, k = idx & 127;
    float v;
    if (n < 256)      v = Wn[(size_t)k * 256 + n];
    else if (n < 384) v = We[(size_t)k * 128 + (n - 256)];
    else              v = We[(size_t)(135 + k) * 128 + (n - 384)];
    Btg[(size_t)n * 128 + k] = (short)f2bf(v);
}

// ---------------------------------------------------------------------------
// K1b: MFMA projection GEMM: A[N,128](fp32->bf16) @ B[128,512]
// Outputs stored BF16: hbf [N,256] (+bias), Pbf [N,128], Qbf [N,128]
// ---------------------------------------------------------------------------
__global__ __launch_bounds__(256) void gemm_mfma(
    const float* __restrict__ A, const float* __restrict__ bn,
    const short* __restrict__ Btg, unsigned short* __restrict__ hbf,
    unsigned short* __restrict__ Pbf, unsigned short* __restrict__ Qbf, int N)
{
    __shared__ __align__(16) short Al[128 * 136];
    __shared__ __align__(16) short Bl[128 * 136];
    int t = threadIdx.x;
    int row0 = blockIdx.x * 128;

    #pragma unroll
    for (int i = 0; i < 16; i++) {
        int idx = t + i * 256;
        int fr = idx >> 5, fc4 = idx & 31;
        int row = row0 + fr;
        float4 v = make_float4(0.f, 0.f, 0.f, 0.f);
        if (row < N) v = *(const float4*)(A + (size_t)row * 128 + fc4 * 4);
        unsigned long long pk =  (unsigned long long)f2bf(v.x)
                              | ((unsigned long long)f2bf(v.y) << 16)
                              | ((unsigned long long)f2bf(v.z) << 32)
                              | ((unsigned long long)f2bf(v.w) << 48);
        *(unsigned long long*)&Al[fr * 136 + fc4 * 4] = pk;
    }
    __syncthreads();

    int w = t >> 6, l = t & 63;
    int lr = l & 15, lg = l >> 4;

    for (int ct = 0; ct < 4; ct++) {
        if (ct > 0) __syncthreads();
        #pragma unroll
        for (int i = 0; i < 8; i++) {
            int idx = t + i * 256;
            int r = idx >> 4, c8 = idx & 15;
            uint4 v = *(const uint4*)(Btg + (size_t)(ct * 128 + r) * 128 + c8 * 8);
            *(uint4*)&Bl[r * 136 + c8 * 8] = v;
        }
        __syncthreads();

        f32x4 acc[2][8];
        #pragma unroll
        for (int fr = 0; fr < 2; fr++)
            #pragma unroll
            for (int fc = 0; fc < 8; fc++) {
                acc[fr][fc][0] = 0.f; acc[fr][fc][1] = 0.f;
                acc[fr][fc][2] = 0.f; acc[fr][fc][3] = 0.f;
            }

        #pragma unroll
        for (int ks = 0; ks < 4; ks++) {
            int k0 = ks * 32 + lg * 8;
            bf16x8 a0 = *(const bf16x8*)&Al[(w * 32 + lr) * 136 + k0];
            bf16x8 a1 = *(const bf16x8*)&Al[(w * 32 + 16 + lr) * 136 + k0];
            #pragma unroll
            for (int fc = 0; fc < 8; fc++) {
                bf16x8 bb = *(const bf16x8*)&Bl[(fc * 16 + lr) * 136 + k0];
                acc[0][fc] = __builtin_amdgcn_mfma_f32_16x16x32_bf16(a0, bb, acc[0][fc], 0, 0, 0);
                acc[1][fc] = __builtin_amdgcn_mfma_f32_16x16x32_bf16(a1, bb, acc[1][fc], 0, 0, 0);
            }
        }

        #pragma unroll
        for (int fc = 0; fc < 8; fc++) {
            int col = fc * 16 + lr;
            float bias = (ct < 2) ? bn[ct * 128 + col] : 0.f;
            #pragma unroll
            for (int fr = 0; fr < 2; fr++) {
                #pragma unroll
                for (int b = 0; b < 4; b++) {
                    int row = row0 + w * 32 + fr * 16 + lg * 4 + b;
                    if (row >= N) continue;
                    unsigned short bv = f2bf(acc[fr][fc][b] + bias);
                    if (ct < 2)       hbf[(size_t)row * 256 + ct * 128 + col] = bv;
                    else if (ct == 2) Pbf[(size_t)row * 128 + col] = bv;
                    else              Qbf[(size_t)row * 128 + col] = bv;
                }
            }
        }
    }
}

// ---------------------------------------------------------------------------
// K2: per-destination degree count
// ---------------------------------------------------------------------------
__global__ void count_kernel(const int* __restrict__ dst, int* __restrict__ deg, int E) {
    int i = blockIdx.x * blockDim.x + threadIdx.x;
    if (i < E) atomicAdd(&deg[dst[i]], 1);
}

// ---------------------------------------------------------------------------
// K3a/b/c: multi-block exclusive scan of deg -> row_start, cursor
// ---------------------------------------------------------------------------
__global__ __launch_bounds__(256) void scan_sum(
    const int* __restrict__ deg, int* __restrict__ bsum, int n)
{
    int b = blockIdx.x, t = threadIdx.x;
    int base = b * 1024 + t * 4;
    int s = 0;
    #pragma unroll
    for (int k = 0; k < 4; k++) { int i = base + k; if (i < n) s += deg[i]; }
    #pragma unroll
    for (int off = 32; off >= 1; off >>= 1) s += __shfl_xor(s, off);
    __shared__ int ws[4];
    if ((t & 63) == 0) ws[t >> 6] = s;
    __syncthreads();
    if (t == 0) bsum[b] = ws[0] + ws[1] + ws[2] + ws[3];
}

__global__ void scan_offsets(const int* __restrict__ bsum, int* __restrict__ boff,
                             int nb, int* __restrict__ row_start, int n)
{
    int acc = 0;
    for (int b = 0; b < nb; b++) { boff[b] = acc; acc += bsum[b]; }
    row_start[n] = acc;
}

__global__ __launch_bounds__(256) void scan_write(
    const int* __restrict__ deg, const int* __restrict__ boff,
    int* __restrict__ row_start, int* __restrict__ cursor, int n)
{
    int b = blockIdx.x, t = threadIdx.x, lane = t & 63, w = t >> 6;
    int base = b * 1024 + t * 4;
    int x0, x1, x2, x3;
    x0 = (base + 0 < n) ? deg[base + 0] : 0;
    x1 = (base + 1 < n) ? deg[base + 1] : 0;
    x2 = (base + 2 < n) ? deg[base + 2] : 0;
    x3 = (base + 3 < n) ? deg[base + 3] : 0;
    int tsum = x0 + x1 + x2 + x3;
    int inc = tsum;
    #pragma unroll
    for (int off = 1; off < 64; off <<= 1) {
        int v = __shfl_up(inc, off);
        if (lane >= off) inc += v;
    }
    int texcl = inc - tsum;
    __shared__ int wsum[4];
    if (lane == 63) wsum[w] = inc;
    __syncthreads();
    int wexcl = 0;
    #pragma unroll
    for (int ww = 0; ww < 4; ww++) if (ww < w) wexcl += wsum[ww];
    int basev = boff[b] + wexcl + texcl;
    int p0 = basev;
    int p1 = p0 + x0;
    int p2 = p1 + x1;
    int p3 = p2 + x2;
    if (base + 0 < n) { row_start[base + 0] = p0; cursor[base + 0] = p0; }
    if (base + 1 < n) { row_start[base + 1] = p1; cursor[base + 1] = p1; }
    if (base + 2 < n) { row_start[base + 2] = p2; cursor[base + 2] = p2; }
    if (base + 3 < n) { row_start[base + 3] = p3; cursor[base + 3] = p3; }
}

// ---------------------------------------------------------------------------
// K4: scatter packed (edge id, src id) into CSR slots — one 8B store
// ---------------------------------------------------------------------------
__global__ void scatter_kernel(const int* __restrict__ dst, const int* __restrict__ src,
                               int* __restrict__ cursor, int2* __restrict__ es, int E) {
    int i = blockIdx.x * blockDim.x + threadIdx.x;
    if (i < E) {
        int pos = atomicAdd(&cursor[dst[i]], 1);
        es[pos] = make_int2(i, src[i]);
    }
}

// ---------------------------------------------------------------------------
// K5: FUSED edge-MLP + online-softmax + aggregation. One wave per dst node.
// Quad-stream unroll-4 (independent softmax states A/B/C/D, merged at end),
// depth-1 prefetch per stream -> 8 gathers + 4 scalar chains in flight.
// ---------------------------------------------------------------------------
__global__ __launch_bounds__(256) void fused_kernel(
    const int* __restrict__ row_start, const int2* __restrict__ ES,
    const float* __restrict__ ef,
    const unsigned short* __restrict__ Pbf, const unsigned short* __restrict__ Qbf,
    const unsigned short* __restrict__ hbf,
    const float* __restrict__ We, const float* __restrict__ Wa,
    float* __restrict__ f_out, float* __restrict__ out, int N)
{
    int t = threadIdx.x;
    int lane = t & 63;
    int n = (int)((blockIdx.x * blockDim.x + t) >> 6);
    if (n >= N) return;
    int c0 = lane * 2;

    float4* O4 = (float4*)out;
    int nu = __builtin_amdgcn_readfirstlane(n);
    int start = row_start[nu];
    int deg   = row_start[nu + 1] - start;
    if (deg == 0) {
        O4[(size_t)n * 64 + lane] = make_float4(0.f, 0.f, 0.f, 0.f);
        return;
    }

    float wf0[7], wf1[7];
    #pragma unroll
    for (int j = 0; j < 7; j++) {
        wf0[j] = We[(size_t)(128 + j) * 128 + c0];
        wf1[j] = We[(size_t)(128 + j) * 128 + c0 + 1];
    }
    int j0 = c0 & 31, j1 = j0 + 1;
    float wv0 = Wa[j0] + Wa[32 + j0] + Wa[64 + j0] + Wa[96 + j0];
    float wv1 = Wa[j1] + Wa[32 + j1] + Wa[64 + j1] + Wa[96 + j1];

    const unsigned* P1 = (const unsigned*)Pbf;   // 2 bf16 cols per lane
    const uint2*    H2 = (const uint2*)hbf;      // 4 bf16 cols per lane

    unsigned qu = ((const unsigned*)Qbf)[(size_t)n * 64 + lane];
    float q0 = bflo(qu), q1 = bfhi(qu);

    // per-stream current state
    #define DSTR(X) \
        float m##X = -1e30f, d##X = 0.f;                                  \
        float4 a##X = make_float4(0.f, 0.f, 0.f, 0.f);                    \
        int e##X = 0; unsigned pu##X = 0; uint2 hu##X = make_uint2(0u,0u);\
        float f##X##0=0.f,f##X##1=0.f,f##X##2=0.f,f##X##3=0.f,            \
              f##X##4=0.f,f##X##5=0.f,f##X##6=0.f;
    // per-stream prefetch regs
    #define DNXT(X) \
        int e##X = 0; unsigned pu##X = 0; uint2 hu##X = make_uint2(0u,0u);\
        float f##X##0=0.f,f##X##1=0.f,f##X##2=0.f,f##X##3=0.f,            \
              f##X##4=0.f,f##X##5=0.f,f##X##6=0.f;

    #define LOADE(pos, X) {                                               \
        int p_ = start + (pos);                                           \
        int2 es_ = ES[p_];                                                \
        e##X = __builtin_amdgcn_readfirstlane(es_.x);                     \
        int s_ = __builtin_amdgcn_readfirstlane(es_.y);                   \
        pu##X = P1[(size_t)s_ * 64 + lane];                               \
        hu##X = H2[(size_t)s_ * 64 + lane];                               \
        const float* ep_ = ef + (size_t)e##X * 7;                         \
        f##X##0 = ep_[0]; f##X##1 = ep_[1]; f##X##2 = ep_[2];             \
        f##X##3 = ep_[3]; f##X##4 = ep_[4]; f##X##5 = ep_[5];             \
        f##X##6 = ep_[6]; }

    #define PROC(X) {                                                     \
        float a0 = bflo(pu##X) + q0, a1 = bfhi(pu##X) + q1;               \
        a0 = fmaf(f##X##0, wf0[0], a0); a1 = fmaf(f##X##0, wf1[0], a1);   \
        a0 = fmaf(f##X##1, wf0[1], a0); a1 = fmaf(f##X##1, wf1[1], a1);   \
        a0 = fmaf(f##X##2, wf0[2], a0); a1 = fmaf(f##X##2, wf1[2], a1);   \
        a0 = fmaf(f##X##3, wf0[3], a0); a1 = fmaf(f##X##3, wf1[3], a1);   \
        a0 = fmaf(f##X##4, wf0[4], a0); a1 = fmaf(f##X##4, wf1[4], a1);   \
        a0 = fmaf(f##X##5, wf0[5], a0); a1 = fmaf(f##X##5, wf1[5], a1);   \
        a0 = fmaf(f##X##6, wf0[6], a0); a1 = fmaf(f##X##6, wf1[6], a1);   \
        float v0 = a0 > 0.f ? a0 : NEG_SLOPE * a0;                        \
        float v1 = a1 > 0.f ? a1 : NEG_SLOPE * a1;                        \
        float2 fv_ = make_float2(v0, v1);                                 \
        unsigned long long u_;                                            \
        __builtin_memcpy(&u_, &fv_, 8);                                   \
        __builtin_nontemporal_store(u_,                                   \
            (unsigned long long*)(f_out + (size_t)e##X * 128 + c0));      \
        float p_ = fmaf(v0, wv0, v1 * wv1);                               \
        p_ += __shfl_xor(p_, 8);                                          \
        p_ += __shfl_xor(p_, 4);                                          \
        p_ += __shfl_xor(p_, 2);                                          \
        p_ += __shfl_xor(p_, 1);                                          \
        float nm_ = fmaxf(m##X, p_);                                      \
        float sc_ = __expf(m##X - nm_);                                   \
        float pe_ = __expf(p_ - nm_);                                     \
        d##X = d##X * sc_ + pe_;                                          \
        float hx0 = bflo(hu##X.x), hx1 = bfhi(hu##X.x);                   \
        float hx2 = bflo(hu##X.y), hx3 = bfhi(hu##X.y);                   \
        a##X.x = fmaf(a##X.x, sc_, pe_ * hx0);                            \
        a##X.y = fmaf(a##X.y, sc_, pe_ * hx1);                            \
        a##X.z = fmaf(a##X.z, sc_, pe_ * hx2);                            \
        a##X.w = fmaf(a##X.w, sc_, pe_ * hx3);                            \
        m##X = nm_; }

    #define ROT(X, Y) { e##X = e##Y; pu##X = pu##Y; hu##X = hu##Y;        \
        f##X##0 = f##Y##0; f##X##1 = f##Y##1; f##X##2 = f##Y##2;          \
        f##X##3 = f##Y##3; f##X##4 = f##Y##4; f##X##5 = f##Y##5;          \
        f##X##6 = f##Y##6; }

    DSTR(A) DSTR(B) DSTR(C) DSTR(D)

    LOADE(0, A);
    if (deg > 1) LOADE(1, B);
    if (deg > 2) LOADE(2, C);
    if (deg > 3) LOADE(3, D);

    for (int k = 0;; k++) {
        int base = 4 * k;
        DNXT(An) DNXT(Bn) DNXT(Cn) DNXT(Dn)
        if (base + 4 < deg) LOADE(base + 4, An);
        if (base + 5 < deg) LOADE(base + 5, Bn);
        if (base + 6 < deg) LOADE(base + 6, Cn);
        if (base + 7 < deg) LOADE(base + 7, Dn);

        PROC(A);
        if (base + 1 < deg) PROC(B);
        if (base + 2 < deg) PROC(C);
        if (base + 3 < deg) PROC(D);

        if (base + 4 >= deg) break;
        ROT(A, An); ROT(B, Bn); ROT(C, Cn); ROT(D, Dn);
    }

    // merge the four softmax states (empty streams contribute 0)
    float nm = fmaxf(fmaxf(mA, mB), fmaxf(mC, mD));
    float scA = __expf(mA - nm), scB = __expf(mB - nm);
    float scC = __expf(mC - nm), scD = __expf(mD - nm);
    float den = dA * scA + dB * scB + dC * scC + dD * scD;
    float r = 1.f / den;
    float4 acc;
    acc.x = (aA.x * scA + aB.x * scB + aC.x * scC + aD.x * scD) * r;
    acc.y = (aA.y * scA + aB.y * scB + aC.y * scC + aD.y * scD) * r;
    acc.z = (aA.z * scA + aB.z * scB + aC.z * scC + aD.z * scD) * r;
    acc.w = (aA.w * scA + aB.w * scB + aC.w * scC + aD.w * scD) * r;
    O4[(size_t)n * 64 + lane] = acc;

    #undef DSTR
    #undef DNXT
    #undef LOADE
    #undef PROC
    #undef ROT
}

// ---------------------------------------------------------------------------
extern "C" void kernel_launch(void* const* d_in, const int* in_sizes, int n_in,
                              void* d_out, int out_size, void* d_ws, size_t ws_size,
                              hipStream_t stream)
{
    const float* nfeats = (const float*)d_in[0];
    const float* efeats = (const float*)d_in[1];
    const int*   src    = (const int*)d_in[2];
    const int*   dst    = (const int*)d_in[3];
    const float* Wn     = (const float*)d_in[4];
    const float* bn     = (const float*)d_in[5];
    const float* We     = (const float*)d_in[6];
    const float* Wa     = (const float*)d_in[7];

    int N = in_sizes[0] / 128;
    int E = in_sizes[2];

    char* ws = (char*)d_ws;
    size_t off = 0;
    unsigned short* hbf = (unsigned short*)(ws + off); off += (size_t)N * 256 * 2;
    unsigned short* Pbf = (unsigned short*)(ws + off); off += (size_t)N * 128 * 2;
    unsigned short* Qbf = (unsigned short*)(ws + off); off += (size_t)N * 128 * 2;
    short* Btg   = (short*)(ws + off); off += (size_t)512 * 128 * 2;
    int2* es       = (int2*)(ws + off); off += (size_t)E * 8;
    int* deg       = (int*)(ws + off); off += (size_t)(N + 1) * 4;
    int* row_start = (int*)(ws + off); off += (size_t)(N + 1) * 4;
    int* cursor    = (int*)(ws + off); off += (size_t)(N + 1) * 4;
    int* bsum      = (int*)(ws + off); off += 1024;
    int* boff      = (int*)(ws + off); off += 1024;

    float* h_out = (float*)d_out;                       // [N, 4, 64]
    float* f_out = (float*)d_out + (size_t)N * 256;     // [E, 4, 32]

    zero_kernel<<<(N + 255) / 256, 256, 0, stream>>>(deg, N);

    bt_prep<<<256, 256, 0, stream>>>(Wn, We, Btg);
    gemm_mfma<<<(N + 127) / 128, 256, 0, stream>>>(nfeats, bn, Btg, hbf, Pbf, Qbf, N);

    count_kernel<<<(E + 255) / 256, 256, 0, stream>>>(dst, deg, E);

    int nb = (N + 1023) / 1024;
    scan_sum<<<nb, 256, 0, stream>>>(deg, bsum, N);
    scan_offsets<<<1, 1, 0, stream>>>(bsum, boff, nb, row_start, N);
    scan_write<<<nb, 256, 0, stream>>>(deg, boff, row_start, cursor, N);

    scatter_kernel<<<(E + 255) / 256, 256, 0, stream>>>(dst, src, cursor, es, E);

    fused_kernel<<<(N + 3) / 4, 256, 0, stream>>>(row_start, es, efeats,
                                                  Pbf, Qbf, hbf, We, Wa,
                                                  f_out, h_out, N);
}